// Round 2
// baseline (4661.364 us; speedup 1.0000x reference)
//
#include <hip/hip_runtime.h>
#include <hip/hip_bf16.h>
#include <math.h>

#define D_IN 256
#define D_H 128
#define D_L 64

// ---------------- degree ----------------
__global__ __launch_bounds__(256) void degree_kernel(const int* __restrict__ dst, int E,
                                                     float* __restrict__ deg) {
    int e = blockIdx.x * 256 + threadIdx.x;
    if (e < E) atomicAdd(&deg[dst[e]], 1.0f);
}

__global__ __launch_bounds__(256) void rsqrt_kernel(float* __restrict__ deg, int n) {
    int i = blockIdx.x * 256 + threadIdx.x;
    if (i < n) deg[i] = rsqrtf(deg[i] + 1.0f);
}

// ---------------- tiled f32 GEMM: C[M,BN] = A[M,K] @ B[K,BN] (BN = full N) ----------------
template<int BM, int BN, int BK, int TM, int TN>
__global__ __launch_bounds__(256) void gemm_f32(const float* __restrict__ A,
                                                const float* __restrict__ B,
                                                float* __restrict__ C, int M, int K) {
    __shared__ float As[BK][BM + 1];
    __shared__ float Bs[BK][BN];
    constexpr int TX = BN / TN;   // threads along N
    constexpr int TY = BM / TM;   // threads along M
    static_assert(TX * TY == 256, "bad tile");
    const int tid = threadIdx.x;
    const int tx = tid % TX, ty = tid / TX;
    const int bm = blockIdx.x * BM;
    float acc[TM][TN] = {};
    for (int bk = 0; bk < K; bk += BK) {
        // A tile: BM x BK, stored transposed As[k][m]
        constexpr int A4 = BM * BK / (4 * 256);
        #pragma unroll
        for (int i = 0; i < A4; ++i) {
            int l = tid + i * 256;
            int r = l / (BK / 4);
            int kv = l % (BK / 4);
            int row = bm + r;
            float4 v = make_float4(0.f, 0.f, 0.f, 0.f);
            if (row < M) v = *(const float4*)&A[(size_t)row * K + bk + kv * 4];
            As[kv * 4 + 0][r] = v.x;
            As[kv * 4 + 1][r] = v.y;
            As[kv * 4 + 2][r] = v.z;
            As[kv * 4 + 3][r] = v.w;
        }
        // B tile: BK x BN, direct
        constexpr int B4 = BK * BN / (4 * 256);
        #pragma unroll
        for (int i = 0; i < B4; ++i) {
            int l = tid + i * 256;
            int k = l / (BN / 4);
            int nv = l % (BN / 4);
            *(float4*)&Bs[k][nv * 4] = *(const float4*)&B[(size_t)(bk + k) * BN + nv * 4];
        }
        __syncthreads();
        #pragma unroll
        for (int k = 0; k < BK; ++k) {
            float a[TM], b[TN];
            #pragma unroll
            for (int i = 0; i < TM; ++i) a[i] = As[k][ty * TM + i];
            #pragma unroll
            for (int j = 0; j < TN; ++j) b[j] = Bs[k][tx * TN + j];
            #pragma unroll
            for (int i = 0; i < TM; ++i)
                #pragma unroll
                for (int j = 0; j < TN; ++j)
                    acc[i][j] = fmaf(a[i], b[j], acc[i][j]);
        }
        __syncthreads();
    }
    #pragma unroll
    for (int i = 0; i < TM; ++i) {
        int row = bm + ty * TM + i;
        if (row < M) {
            #pragma unroll
            for (int j = 0; j < TN; j += 4) {
                *(float4*)&C[(size_t)row * BN + tx * TN + j] =
                    make_float4(acc[i][j], acc[i][j + 1], acc[i][j + 2], acc[i][j + 3]);
            }
        }
    }
}

// ---------------- scatter-add aggregation (atomics) ----------------
template<int D>
__global__ __launch_bounds__(256) void scatter_kernel(const float* __restrict__ hlin,
                                                      const int* __restrict__ src,
                                                      const int* __restrict__ dst,
                                                      const float* __restrict__ di,
                                                      float* __restrict__ agg, int E) {
    unsigned t = blockIdx.x * 256u + threadIdx.x;
    unsigned e = t / (D / 4);
    unsigned c = t % (D / 4);
    if (e >= (unsigned)E) return;
    int s = src[e], d = dst[e];
    float coef = di[s] * di[d];
    float4 v = *(const float4*)&hlin[(size_t)s * D + c * 4];
    float* p = &agg[(size_t)d * D + c * 4];
    atomicAdd(p + 0, v.x * coef);
    atomicAdd(p + 1, v.y * coef);
    atomicAdd(p + 2, v.z * coef);
    atomicAdd(p + 3, v.w * coef);
}

// ---------------- self-loop + bias (+ relu) ----------------
template<int D, bool RELU>
__global__ __launch_bounds__(256) void finalize_kernel(float* __restrict__ agg,
                                                       const float* __restrict__ hlin,
                                                       const float* __restrict__ di,
                                                       const float* __restrict__ bias, int N) {
    int t = blockIdx.x * 256 + threadIdx.x;
    int total = N * (D / 4);
    if (t >= total) return;
    int row = t / (D / 4);
    int c = t % (D / 4);
    float s = di[row];
    s *= s;
    float4 a = ((float4*)agg)[t];
    float4 h = ((const float4*)hlin)[t];
    a.x += h.x * s + bias[c * 4 + 0];
    a.y += h.y * s + bias[c * 4 + 1];
    a.z += h.z * s + bias[c * 4 + 2];
    a.w += h.w * s + bias[c * 4 + 3];
    if (RELU) {
        a.x = fmaxf(a.x, 0.f);
        a.y = fmaxf(a.y, 0.f);
        a.z = fmaxf(a.z, 0.f);
        a.w = fmaxf(a.w, 0.f);
    }
    ((float4*)agg)[t] = a;
}

// ---------------- fused gather + MLP + sigmoid over eval edges ----------------
__global__ __launch_bounds__(256) void eval_kernel(const float* __restrict__ z,
                                                   const int* __restrict__ es,
                                                   const int* __restrict__ ed,
                                                   const float* __restrict__ Wf1,
                                                   const float* __restrict__ bf1,
                                                   const float* __restrict__ Wf2,
                                                   const float* __restrict__ bf2,
                                                   float* __restrict__ out, int EV) {
    __shared__ float pairT[128][68];   // feature-major: pairT[k][edge], padded stride 68
    __shared__ float W1s[128][64];
    __shared__ float W2s[64], b1s[64];
    const int tid = threadIdx.x;
    const int e0 = blockIdx.x * 64;
    // stage Wf1 (32KB)
    for (int i = tid; i < 128 * 64 / 4; i += 256)
        ((float4*)W1s)[i] = ((const float4*)Wf1)[i];
    if (tid < 64) { W2s[tid] = Wf2[tid]; b1s[tid] = bf1[tid]; }
    // gather pair tile: 64 edges x 128 features; lane = edge -> conflict-free LDS writes
    for (int l = tid; l < 2048; l += 256) {
        int e = l & 63, c = l >> 6;     // c in [0,32): float4 chunk of the 128-dim feature
        int ee = e0 + e;
        int koff = (c < 16) ? c * 4 : 64 + (c - 16) * 4;
        float4 v = make_float4(0.f, 0.f, 0.f, 0.f);
        if (ee < EV) {
            int row = (c < 16) ? es[ee] : ed[ee];
            v = *(const float4*)&z[(size_t)row * 64 + (koff & 63)];
        }
        pairT[koff + 0][e] = v.x;
        pairT[koff + 1][e] = v.y;
        pairT[koff + 2][e] = v.z;
        pairT[koff + 3][e] = v.w;
    }
    __syncthreads();
    const int te = tid >> 4, th = tid & 15;   // edge group / hidden group
    float acc[4][4] = {};
    for (int k = 0; k < 128; ++k) {
        float4 av = *(const float4*)&pairT[k][te * 4];
        float4 bv = *(const float4*)&W1s[k][th * 4];
        float a4[4] = {av.x, av.y, av.z, av.w};
        float b4[4] = {bv.x, bv.y, bv.z, bv.w};
        #pragma unroll
        for (int i = 0; i < 4; ++i)
            #pragma unroll
            for (int j = 0; j < 4; ++j)
                acc[i][j] = fmaf(a4[i], b4[j], acc[i][j]);
    }
    // relu + second layer partial
    float part[4];
    #pragma unroll
    for (int i = 0; i < 4; ++i) {
        float p = 0.f;
        #pragma unroll
        for (int j = 0; j < 4; ++j) {
            float h = acc[i][j] + b1s[th * 4 + j];
            h = fmaxf(h, 0.f);
            p = fmaf(h, W2s[th * 4 + j], p);
        }
        part[i] = p;
    }
    // reduce across the 16 hidden-group lanes (consecutive within wave)
    #pragma unroll
    for (int m = 1; m < 16; m <<= 1) {
        #pragma unroll
        for (int i = 0; i < 4; ++i) part[i] += __shfl_xor(part[i], m, 64);
    }
    if (th == 0) {
        float b2v = bf2[0];
        #pragma unroll
        for (int i = 0; i < 4; ++i) {
            int ee = e0 + te * 4 + i;
            if (ee < EV) out[ee] = 1.f / (1.f + expf(-(part[i] + b2v)));
        }
    }
}

extern "C" void kernel_launch(void* const* d_in, const int* in_sizes, int n_in,
                              void* d_out, int out_size, void* d_ws, size_t ws_size,
                              hipStream_t stream) {
    const float* x   = (const float*)d_in[0];
    const int* eidx  = (const int*)d_in[1];
    const int* evidx = (const int*)d_in[2];
    const float* W1  = (const float*)d_in[3];
    const float* b1  = (const float*)d_in[4];
    const float* W2  = (const float*)d_in[5];
    const float* b2  = (const float*)d_in[6];
    const float* Wf1 = (const float*)d_in[7];
    const float* bf1 = (const float*)d_in[8];
    const float* Wf2 = (const float*)d_in[9];
    const float* bf2 = (const float*)d_in[10];
    const int E  = in_sizes[1] / 2;
    const int EV = in_sizes[2] / 2;
    const int N  = in_sizes[0] / D_IN;
    const int* esrc = eidx;
    const int* edst = eidx + E;
    const int* es = evidx;
    const int* ed = evidx + EV;
    float* out = (float*)d_out;

    // workspace layout (total ~58 MB):
    //   di   @ 0        : N f32 (deg_isqrt)           0.2 MB
    //   bufA @ 1 MB     : N*128 f32 ping              25.6 MB
    //   bufB @ 33 MB    : N*128 f32 pong              25.6 MB
    char* ws = (char*)d_ws;
    float* di   = (float*)(ws);
    float* bufA = (float*)(ws + (1 << 20));
    float* bufB = (float*)(ws + (1 << 20) + ((size_t)32 << 20));

    // degree (with self-loop) -> deg_isqrt, in place
    hipMemsetAsync(di, 0, (size_t)N * sizeof(float), stream);
    degree_kernel<<<(E + 255) / 256, 256, 0, stream>>>(edst, E, di);
    rsqrt_kernel<<<(N + 255) / 256, 256, 0, stream>>>(di, N);

    // conv1: h1 = x @ W1 ; agg ; self-loop + b1 + relu
    gemm_f32<64, 128, 64, 8, 4><<<(N + 63) / 64, 256, 0, stream>>>(x, W1, bufA, N, D_IN);
    hipMemsetAsync(bufB, 0, (size_t)N * D_H * sizeof(float), stream);
    scatter_kernel<128><<<(unsigned)(((size_t)E * 32 + 255) / 256), 256, 0, stream>>>(
        bufA, esrc, edst, di, bufB, E);
    finalize_kernel<128, true><<<(unsigned)(((size_t)N * 32 + 255) / 256), 256, 0, stream>>>(
        bufB, bufA, di, b1, N);

    // conv2: h2 = h @ W2 ; agg ; self-loop + b2
    gemm_f32<64, 64, 64, 4, 4><<<(N + 63) / 64, 256, 0, stream>>>(bufB, W2, bufA, N, D_H);
    hipMemsetAsync(bufB, 0, (size_t)N * D_L * sizeof(float), stream);
    scatter_kernel<64><<<(unsigned)(((size_t)E * 16 + 255) / 256), 256, 0, stream>>>(
        bufA, esrc, edst, di, bufB, E);
    finalize_kernel<64, false><<<(unsigned)(((size_t)N * 16 + 255) / 256), 256, 0, stream>>>(
        bufB, bufA, di, b2, N);

    // eval MLP + sigmoid
    eval_kernel<<<(EV + 63) / 64, 256, 0, stream>>>(bufB, es, ed, Wf1, bf1, Wf2, bf2, out, EV);
}

// Round 3
// 1005.614 us; speedup vs baseline: 4.6353x; 4.6353x over previous
//
#include <hip/hip_runtime.h>
#include <hip/hip_bf16.h>
#include <math.h>

#define D_IN 256
#define D_H 128
#define D_L 64

// ---------------- degree (int histogram) ----------------
__global__ __launch_bounds__(256) void degree_kernel(const int* __restrict__ dst, int E,
                                                     int* __restrict__ degi) {
    int e = blockIdx.x * 256 + threadIdx.x;
    if (e < E) atomicAdd(&degi[dst[e]], 1);
}

__global__ __launch_bounds__(256) void rsqrt_kernel(const int* __restrict__ degi,
                                                    float* __restrict__ di, int n) {
    int i = blockIdx.x * 256 + threadIdx.x;
    if (i < n) di[i] = rsqrtf((float)degi[i] + 1.0f);
}

// ---------------- single-block exclusive scan over degi -> rowptr (+cursor copy) ----------------
__global__ __launch_bounds__(1024) void scan_kernel(const int* __restrict__ degi,
                                                    int* __restrict__ rowptr,
                                                    int* __restrict__ cursor, int n) {
    __shared__ int sums[1024];
    const int tid = threadIdx.x;
    const int chunk = (n + 1023) / 1024;
    const int base = tid * chunk;
    int s = 0;
    for (int i = 0; i < chunk; ++i) {
        int idx = base + i;
        if (idx < n) s += degi[idx];
    }
    sums[tid] = s;
    __syncthreads();
    for (int off = 1; off < 1024; off <<= 1) {
        int v = (tid >= off) ? sums[tid - off] : 0;
        __syncthreads();
        sums[tid] += v;
        __syncthreads();
    }
    int run = (tid == 0) ? 0 : sums[tid - 1];
    for (int i = 0; i < chunk; ++i) {
        int idx = base + i;
        if (idx < n) {
            rowptr[idx] = run;
            cursor[idx] = run;
            run += degi[idx];
        }
    }
    if (tid == 1023) rowptr[n] = sums[1023];
}

// ---------------- CSR fill: bucket src by dst ----------------
__global__ __launch_bounds__(256) void fill_csr_kernel(const int* __restrict__ src,
                                                       const int* __restrict__ dst,
                                                       int* __restrict__ cursor,
                                                       int* __restrict__ csr_src, int E) {
    int e = blockIdx.x * 256 + threadIdx.x;
    if (e < E) {
        int pos = atomicAdd(&cursor[dst[e]], 1);
        csr_src[pos] = src[e];
    }
}

// ---------------- tiled f32 GEMM: C[M,BN] = A[M,K] @ B[K,BN] (BN = full N) ----------------
template<int BM, int BN, int BK, int TM, int TN>
__global__ __launch_bounds__(256) void gemm_f32(const float* __restrict__ A,
                                                const float* __restrict__ B,
                                                float* __restrict__ C, int M, int K) {
    __shared__ float As[BK][BM + 1];
    __shared__ float Bs[BK][BN];
    constexpr int TX = BN / TN;
    constexpr int TY = BM / TM;
    static_assert(TX * TY == 256, "bad tile");
    const int tid = threadIdx.x;
    const int tx = tid % TX, ty = tid / TX;
    const int bm = blockIdx.x * BM;
    float acc[TM][TN] = {};
    for (int bk = 0; bk < K; bk += BK) {
        constexpr int A4 = BM * BK / (4 * 256);
        #pragma unroll
        for (int i = 0; i < A4; ++i) {
            int l = tid + i * 256;
            int r = l / (BK / 4);
            int kv = l % (BK / 4);
            int row = bm + r;
            float4 v = make_float4(0.f, 0.f, 0.f, 0.f);
            if (row < M) v = *(const float4*)&A[(size_t)row * K + bk + kv * 4];
            As[kv * 4 + 0][r] = v.x;
            As[kv * 4 + 1][r] = v.y;
            As[kv * 4 + 2][r] = v.z;
            As[kv * 4 + 3][r] = v.w;
        }
        constexpr int B4 = BK * BN / (4 * 256);
        #pragma unroll
        for (int i = 0; i < B4; ++i) {
            int l = tid + i * 256;
            int k = l / (BN / 4);
            int nv = l % (BN / 4);
            *(float4*)&Bs[k][nv * 4] = *(const float4*)&B[(size_t)(bk + k) * BN + nv * 4];
        }
        __syncthreads();
        #pragma unroll
        for (int k = 0; k < BK; ++k) {
            float a[TM], b[TN];
            #pragma unroll
            for (int i = 0; i < TM; ++i) a[i] = As[k][ty * TM + i];
            #pragma unroll
            for (int j = 0; j < TN; ++j) b[j] = Bs[k][tx * TN + j];
            #pragma unroll
            for (int i = 0; i < TM; ++i)
                #pragma unroll
                for (int j = 0; j < TN; ++j)
                    acc[i][j] = fmaf(a[i], b[j], acc[i][j]);
        }
        __syncthreads();
    }
    #pragma unroll
    for (int i = 0; i < TM; ++i) {
        int row = bm + ty * TM + i;
        if (row < M) {
            #pragma unroll
            for (int j = 0; j < TN; j += 4) {
                *(float4*)&C[(size_t)row * BN + tx * TN + j] =
                    make_float4(acc[i][j], acc[i][j + 1], acc[i][j + 2], acc[i][j + 3]);
            }
        }
    }
}

// ---------------- CSR aggregation, one wave per dst node, fused self-loop+bias(+relu) ----------------
template<int D, bool RELU>
__global__ __launch_bounds__(256) void agg_kernel(const float* __restrict__ hlin,
                                                  const int* __restrict__ rowptr,
                                                  const int* __restrict__ csr_src,
                                                  const float* __restrict__ di,
                                                  const float* __restrict__ bias,
                                                  float* __restrict__ outp, int N) {
    const int wave = (blockIdx.x * 256 + threadIdx.x) >> 6;
    const int lane = threadIdx.x & 63;
    if (wave >= N) return;
    const int d = wave;
    const int start = rowptr[d], end = rowptr[d + 1];
    const float did = di[d];
    if constexpr (D == 128) {
        const float2* h2 = (const float2*)hlin;
        float2 acc = make_float2(0.f, 0.f);
        for (int base = start; base < end; base += 64) {
            int idx = base + lane;
            bool valid = idx < end;
            int mys = valid ? csr_src[idx] : 0;
            float myc = valid ? di[mys] : 0.f;
            int cnt = min(64, end - base);
            for (int j = 0; j < cnt; ++j) {
                int s = __shfl(mys, j, 64);
                float coef = __shfl(myc, j, 64) * did;
                float2 v = h2[(size_t)s * 64 + lane];
                acc.x = fmaf(v.x, coef, acc.x);
                acc.y = fmaf(v.y, coef, acc.y);
            }
        }
        float sl = did * did;
        float2 hv = h2[(size_t)d * 64 + lane];
        float2 bv = ((const float2*)bias)[lane];
        float ox = acc.x + hv.x * sl + bv.x;
        float oy = acc.y + hv.y * sl + bv.y;
        if (RELU) { ox = fmaxf(ox, 0.f); oy = fmaxf(oy, 0.f); }
        ((float2*)outp)[(size_t)d * 64 + lane] = make_float2(ox, oy);
    } else {
        float acc = 0.f;
        for (int base = start; base < end; base += 64) {
            int idx = base + lane;
            bool valid = idx < end;
            int mys = valid ? csr_src[idx] : 0;
            float myc = valid ? di[mys] : 0.f;
            int cnt = min(64, end - base);
            for (int j = 0; j < cnt; ++j) {
                int s = __shfl(mys, j, 64);
                float coef = __shfl(myc, j, 64) * did;
                acc = fmaf(hlin[(size_t)s * 64 + lane], coef, acc);
            }
        }
        float sl = did * did;
        float v = acc + hlin[(size_t)d * 64 + lane] * sl + bias[lane];
        if (RELU) v = fmaxf(v, 0.f);
        outp[(size_t)d * 64 + lane] = v;
    }
}

// ---------------- fused gather + MLP + sigmoid over eval edges ----------------
__global__ __launch_bounds__(256) void eval_kernel(const float* __restrict__ z,
                                                   const int* __restrict__ es,
                                                   const int* __restrict__ ed,
                                                   const float* __restrict__ Wf1,
                                                   const float* __restrict__ bf1,
                                                   const float* __restrict__ Wf2,
                                                   const float* __restrict__ bf2,
                                                   float* __restrict__ out, int EV) {
    __shared__ float pairT[128][68];   // feature-major, padded stride
    __shared__ float W1s[128][64];
    __shared__ float W2s[64], b1s[64];
    const int tid = threadIdx.x;
    const int e0 = blockIdx.x * 64;
    for (int i = tid; i < 128 * 64 / 4; i += 256)
        ((float4*)W1s)[i] = ((const float4*)Wf1)[i];
    if (tid < 64) { W2s[tid] = Wf2[tid]; b1s[tid] = bf1[tid]; }
    for (int l = tid; l < 2048; l += 256) {
        int e = l & 63, c = l >> 6;
        int ee = e0 + e;
        int koff = (c < 16) ? c * 4 : 64 + (c - 16) * 4;
        float4 v = make_float4(0.f, 0.f, 0.f, 0.f);
        if (ee < EV) {
            int row = (c < 16) ? es[ee] : ed[ee];
            v = *(const float4*)&z[(size_t)row * 64 + (koff & 63)];
        }
        pairT[koff + 0][e] = v.x;
        pairT[koff + 1][e] = v.y;
        pairT[koff + 2][e] = v.z;
        pairT[koff + 3][e] = v.w;
    }
    __syncthreads();
    const int te = tid >> 4, th = tid & 15;
    float acc[4][4] = {};
    for (int k = 0; k < 128; ++k) {
        float4 av = *(const float4*)&pairT[k][te * 4];
        float4 bv = *(const float4*)&W1s[k][th * 4];
        float a4[4] = {av.x, av.y, av.z, av.w};
        float b4[4] = {bv.x, bv.y, bv.z, bv.w};
        #pragma unroll
        for (int i = 0; i < 4; ++i)
            #pragma unroll
            for (int j = 0; j < 4; ++j)
                acc[i][j] = fmaf(a4[i], b4[j], acc[i][j]);
    }
    float part[4];
    #pragma unroll
    for (int i = 0; i < 4; ++i) {
        float p = 0.f;
        #pragma unroll
        for (int j = 0; j < 4; ++j) {
            float h = acc[i][j] + b1s[th * 4 + j];
            h = fmaxf(h, 0.f);
            p = fmaf(h, W2s[th * 4 + j], p);
        }
        part[i] = p;
    }
    #pragma unroll
    for (int m = 1; m < 16; m <<= 1) {
        #pragma unroll
        for (int i = 0; i < 4; ++i) part[i] += __shfl_xor(part[i], m, 64);
    }
    if (th == 0) {
        float b2v = bf2[0];
        #pragma unroll
        for (int i = 0; i < 4; ++i) {
            int ee = e0 + te * 4 + i;
            if (ee < EV) out[ee] = 1.f / (1.f + expf(-(part[i] + b2v)));
        }
    }
}

extern "C" void kernel_launch(void* const* d_in, const int* in_sizes, int n_in,
                              void* d_out, int out_size, void* d_ws, size_t ws_size,
                              hipStream_t stream) {
    const float* x   = (const float*)d_in[0];
    const int* eidx  = (const int*)d_in[1];
    const int* evidx = (const int*)d_in[2];
    const float* W1  = (const float*)d_in[3];
    const float* b1  = (const float*)d_in[4];
    const float* W2  = (const float*)d_in[5];
    const float* b2  = (const float*)d_in[6];
    const float* Wf1 = (const float*)d_in[7];
    const float* bf1 = (const float*)d_in[8];
    const float* Wf2 = (const float*)d_in[9];
    const float* bf2 = (const float*)d_in[10];
    const int E  = in_sizes[1] / 2;
    const int EV = in_sizes[2] / 2;
    const int N  = in_sizes[0] / D_IN;
    const int* esrc = eidx;
    const int* edst = eidx + E;
    const int* es = evidx;
    const int* ed = evidx + EV;
    float* out = (float*)d_out;

    // workspace layout (bytes, total ~56.5 MB):
    //   di      @ 0       : N f32
    //   degi    @ 256K    : N i32
    //   rowptr  @ 512K    : (N+1) i32
    //   cursor  @ 768K    : N i32
    //   csr_src @ 1M      : E i32 (6.4 MB)
    //   bufA    @ 7.5M    : N*128 f32 (25.6 MB)   [conv1 hlin; later hlin2 | z]
    //   bufB    @ 32M     : N*128 f32 (25.6 MB)   [conv1 out h]
    char* ws = (char*)d_ws;
    float* di     = (float*)(ws);
    int*   degi   = (int*)(ws + (256 << 10));
    int*   rowptr = (int*)(ws + (512 << 10));
    int*   cursor = (int*)(ws + (768 << 10));
    int*   csrsrc = (int*)(ws + (1 << 20));
    float* bufA   = (float*)(ws + ((size_t)75 << 17));          // 7.5 MB
    float* bufB   = (float*)(ws + ((size_t)32 << 20));          // 32 MB
    float* hlin2  = bufA;                    // N*64
    float* zfeat  = bufA + (size_t)N * D_L;  // N*64

    // ---- CSR build (once, reused by both convs) ----
    hipMemsetAsync(degi, 0, (size_t)N * sizeof(int), stream);
    degree_kernel<<<(E + 255) / 256, 256, 0, stream>>>(edst, E, degi);
    scan_kernel<<<1, 1024, 0, stream>>>(degi, rowptr, cursor, N);
    rsqrt_kernel<<<(N + 255) / 256, 256, 0, stream>>>(degi, di, N);
    fill_csr_kernel<<<(E + 255) / 256, 256, 0, stream>>>(esrc, edst, cursor, csrsrc, E);

    // ---- conv1: hlin = x@W1 ; agg+selfloop+b1+relu -> h (bufB) ----
    gemm_f32<64, 128, 64, 8, 4><<<(N + 63) / 64, 256, 0, stream>>>(x, W1, bufA, N, D_IN);
    agg_kernel<128, true><<<(N + 3) / 4, 256, 0, stream>>>(bufA, rowptr, csrsrc, di, b1, bufB, N);

    // ---- conv2: hlin2 = h@W2 ; agg+selfloop+b2 -> z ----
    gemm_f32<64, 64, 64, 4, 4><<<(N + 63) / 64, 256, 0, stream>>>(bufB, W2, hlin2, N, D_H);
    agg_kernel<64, false><<<(N + 3) / 4, 256, 0, stream>>>(hlin2, rowptr, csrsrc, di, b2, zfeat, N);

    // ---- eval MLP + sigmoid ----
    eval_kernel<<<(EV + 63) / 64, 256, 0, stream>>>(zfeat, es, ed, Wf1, bf1, Wf2, bf2, out, EV);
}

// Round 4
// 761.732 us; speedup vs baseline: 6.1194x; 1.3202x over previous
//
#include <hip/hip_runtime.h>
#include <hip/hip_bf16.h>
#include <math.h>

#define D_IN 256
#define D_H 128
#define D_L 64

typedef __attribute__((ext_vector_type(8))) short bf16x8;
typedef __attribute__((ext_vector_type(4))) float f32x4;

__device__ __forceinline__ short f2bs(float f) {
    __hip_bfloat16 b = __float2bfloat16(f);
    return *reinterpret_cast<short*>(&b);
}
__device__ __forceinline__ float bs2f_lo(unsigned v) { return __uint_as_float(v << 16); }
__device__ __forceinline__ float bs2f_hi(unsigned v) { return __uint_as_float(v & 0xffff0000u); }

// ---------------- degree (int histogram) ----------------
__global__ __launch_bounds__(256) void degree_kernel(const int* __restrict__ dst, int E,
                                                     int* __restrict__ degi) {
    int e = blockIdx.x * 256 + threadIdx.x;
    if (e < E) atomicAdd(&degi[dst[e]], 1);
}

__global__ __launch_bounds__(256) void rsqrt_kernel(const int* __restrict__ degi,
                                                    float* __restrict__ di, int n) {
    int i = blockIdx.x * 256 + threadIdx.x;
    if (i < n) di[i] = rsqrtf((float)degi[i] + 1.0f);
}

// ---------------- single-block exclusive scan over degi -> rowptr (+cursor) ----------------
__global__ __launch_bounds__(1024) void scan_kernel(const int* __restrict__ degi,
                                                    int* __restrict__ rowptr,
                                                    int* __restrict__ cursor, int n) {
    __shared__ int sums[1024];
    const int tid = threadIdx.x;
    const int chunk = (n + 1023) / 1024;
    const int base = tid * chunk;
    int s = 0;
    for (int i = 0; i < chunk; ++i) {
        int idx = base + i;
        if (idx < n) s += degi[idx];
    }
    sums[tid] = s;
    __syncthreads();
    for (int off = 1; off < 1024; off <<= 1) {
        int v = (tid >= off) ? sums[tid - off] : 0;
        __syncthreads();
        sums[tid] += v;
        __syncthreads();
    }
    int run = (tid == 0) ? 0 : sums[tid - 1];
    for (int i = 0; i < chunk; ++i) {
        int idx = base + i;
        if (idx < n) {
            rowptr[idx] = run;
            cursor[idx] = run;
            run += degi[idx];
        }
    }
    if (tid == 1023) rowptr[n] = sums[1023];
}

// ---------------- CSR fill: bucket src by dst ----------------
__global__ __launch_bounds__(256) void fill_csr_kernel(const int* __restrict__ src,
                                                       const int* __restrict__ dst,
                                                       int* __restrict__ cursor,
                                                       int* __restrict__ csr_src, int E) {
    int e = blockIdx.x * 256 + threadIdx.x;
    if (e < E) {
        int pos = atomicAdd(&cursor[dst[e]], 1);
        csr_src[pos] = src[e];
    }
}

// ---------------- tiled f32 GEMM, bf16 output: C[M,BN] = bf16(A[M,K] @ B[K,BN]) ----------------
template<int BM, int BN, int BK, int TM, int TN>
__global__ __launch_bounds__(256) void gemm_bf16out(const float* __restrict__ A,
                                                    const float* __restrict__ B,
                                                    short* __restrict__ C, int M, int K) {
    __shared__ float As[BK][BM + 1];
    __shared__ float Bs[BK][BN];
    constexpr int TX = BN / TN;
    constexpr int TY = BM / TM;
    static_assert(TX * TY == 256, "bad tile");
    const int tid = threadIdx.x;
    const int tx = tid % TX, ty = tid / TX;
    const int bm = blockIdx.x * BM;
    float acc[TM][TN] = {};
    for (int bk = 0; bk < K; bk += BK) {
        constexpr int A4 = BM * BK / (4 * 256);
        #pragma unroll
        for (int i = 0; i < A4; ++i) {
            int l = tid + i * 256;
            int r = l / (BK / 4);
            int kv = l % (BK / 4);
            int row = bm + r;
            float4 v = make_float4(0.f, 0.f, 0.f, 0.f);
            if (row < M) v = *(const float4*)&A[(size_t)row * K + bk + kv * 4];
            As[kv * 4 + 0][r] = v.x;
            As[kv * 4 + 1][r] = v.y;
            As[kv * 4 + 2][r] = v.z;
            As[kv * 4 + 3][r] = v.w;
        }
        constexpr int B4 = BK * BN / (4 * 256);
        #pragma unroll
        for (int i = 0; i < B4; ++i) {
            int l = tid + i * 256;
            int k = l / (BN / 4);
            int nv = l % (BN / 4);
            *(float4*)&Bs[k][nv * 4] = *(const float4*)&B[(size_t)(bk + k) * BN + nv * 4];
        }
        __syncthreads();
        #pragma unroll
        for (int k = 0; k < BK; ++k) {
            float a[TM], b[TN];
            #pragma unroll
            for (int i = 0; i < TM; ++i) a[i] = As[k][ty * TM + i];
            #pragma unroll
            for (int j = 0; j < TN; ++j) b[j] = Bs[k][tx * TN + j];
            #pragma unroll
            for (int i = 0; i < TM; ++i)
                #pragma unroll
                for (int j = 0; j < TN; ++j)
                    acc[i][j] = fmaf(a[i], b[j], acc[i][j]);
        }
        __syncthreads();
    }
    #pragma unroll
    for (int i = 0; i < TM; ++i) {
        int row = bm + ty * TM + i;
        if (row < M) {
            #pragma unroll
            for (int j = 0; j < TN; j += 4) {
                short4 o;
                o.x = f2bs(acc[i][j + 0]);
                o.y = f2bs(acc[i][j + 1]);
                o.z = f2bs(acc[i][j + 2]);
                o.w = f2bs(acc[i][j + 3]);
                *(short4*)&C[(size_t)row * BN + tx * TN + j] = o;
            }
        }
    }
}

// ---------------- CSR aggregation (bf16 gather, f32 accumulate), fused epilogue ----------------
template<int D, bool RELU, bool OUT_BF16>
__global__ __launch_bounds__(256) void agg_kernel(const short* __restrict__ hb,
                                                  const int* __restrict__ rowptr,
                                                  const int* __restrict__ csr_src,
                                                  const float* __restrict__ di,
                                                  const float* __restrict__ bias,
                                                  float* __restrict__ outf,
                                                  short* __restrict__ outb, int N) {
    const int wave = (blockIdx.x * 256 + threadIdx.x) >> 6;
    const int lane = threadIdx.x & 63;
    if (wave >= N) return;
    const int d = wave;
    const int start = rowptr[d], end = rowptr[d + 1];
    const float did = di[d];
    if constexpr (D == 128) {
        const unsigned* h2 = (const unsigned*)hb;   // 2 bf16 per word
        float ax = 0.f, ay = 0.f;
        for (int base = start; base < end; base += 64) {
            int idx = base + lane;
            bool valid = idx < end;
            int mys = valid ? csr_src[idx] : 0;
            float myc = valid ? di[mys] : 0.f;
            int cnt = min(64, end - base);
            for (int j = 0; j < cnt; ++j) {
                int s = __shfl(mys, j, 64);
                float coef = __shfl(myc, j, 64) * did;
                unsigned v = h2[(size_t)s * 64 + lane];
                ax = fmaf(bs2f_lo(v), coef, ax);
                ay = fmaf(bs2f_hi(v), coef, ay);
            }
        }
        float sl = did * did;
        unsigned hv = h2[(size_t)d * 64 + lane];
        float2 bv = ((const float2*)bias)[lane];
        float ox = ax + bs2f_lo(hv) * sl + bv.x;
        float oy = ay + bs2f_hi(hv) * sl + bv.y;
        if (RELU) { ox = fmaxf(ox, 0.f); oy = fmaxf(oy, 0.f); }
        if constexpr (OUT_BF16) {
            unsigned o = ((unsigned)(unsigned short)f2bs(oy) << 16) |
                         (unsigned)(unsigned short)f2bs(ox);
            ((unsigned*)outb)[(size_t)d * 64 + lane] = o;
        } else {
            ((float2*)outf)[(size_t)d * 64 + lane] = make_float2(ox, oy);
        }
    } else {
        const unsigned short* h1 = (const unsigned short*)hb;
        float acc = 0.f;
        for (int base = start; base < end; base += 64) {
            int idx = base + lane;
            bool valid = idx < end;
            int mys = valid ? csr_src[idx] : 0;
            float myc = valid ? di[mys] : 0.f;
            int cnt = min(64, end - base);
            for (int j = 0; j < cnt; ++j) {
                int s = __shfl(mys, j, 64);
                float coef = __shfl(myc, j, 64) * did;
                float hv = __uint_as_float(((unsigned)h1[(size_t)s * 64 + lane]) << 16);
                acc = fmaf(hv, coef, acc);
            }
        }
        float sl = did * did;
        float hd = __uint_as_float(((unsigned)h1[(size_t)d * 64 + lane]) << 16);
        float v = acc + hd * sl + bias[lane];
        if (RELU) v = fmaxf(v, 0.f);
        if constexpr (OUT_BF16) {
            outb[(size_t)d * 64 + lane] = f2bs(v);
        } else {
            outf[(size_t)d * 64 + lane] = v;
        }
    }
}

// ---------------- eval: gather z (bf16) + MFMA MLP + sigmoid ----------------
// Per wave-iteration: 16 edges. A = pair[16][128] bf16 (gathered), B = Wf1 bf16 (in regs).
// mfma_f32_16x16x32_bf16: A lane l -> row l&15, k=(l>>4)*8+j ; B lane l -> k=(l>>4)*8+j, col l&15
// C lane l -> col l&15, row (l>>4)*4+reg.
__global__ __launch_bounds__(256) void eval_mfma_kernel(const short* __restrict__ zb,
                                                        const int* __restrict__ es,
                                                        const int* __restrict__ ed,
                                                        const float* __restrict__ Wf1,
                                                        const float* __restrict__ bf1,
                                                        const float* __restrict__ Wf2,
                                                        const float* __restrict__ bf2,
                                                        float* __restrict__ out, int EV) {
    const int tid = threadIdx.x;
    const int w = tid >> 6;
    const int l = tid & 63;
    const int lr = l & 15;    // A-row / C-col index
    const int lg = l >> 4;    // k-group / C-row-group
    // stage Wf1 fragments in registers (64 VGPR), f32 -> bf16
    bf16x8 bfrag[4][4];       // [kk][ct]
    #pragma unroll
    for (int kk = 0; kk < 4; ++kk)
        #pragma unroll
        for (int ct = 0; ct < 4; ++ct) {
            bf16x8 t;
            #pragma unroll
            for (int j = 0; j < 8; ++j)
                t[j] = f2bs(Wf1[(size_t)(kk * 32 + lg * 8 + j) * 64 + ct * 16 + lr]);
            bfrag[kk][ct] = t;
        }
    float b1r[4], w2r[4];
    #pragma unroll
    for (int ct = 0; ct < 4; ++ct) {
        b1r[ct] = bf1[ct * 16 + lr];
        w2r[ct] = Wf2[ct * 16 + lr];
    }
    const float b2v = bf2[0];

    const int eb = blockIdx.x * 1024;
    for (int t = 0; t < 16; ++t) {
        const int wbase = eb + t * 64 + w * 16;
        int edge = wbase + lr;
        int ec = edge < EV ? edge : 0;
        int ns = es[ec], nd = ed[ec];
        const short* za = zb + (size_t)ns * 64 + lg * 8;
        const short* zc = zb + (size_t)nd * 64 + lg * 8;
        bf16x8 a0 = *(const bf16x8*)(za);
        bf16x8 a1 = *(const bf16x8*)(za + 32);
        bf16x8 a2 = *(const bf16x8*)(zc);
        bf16x8 a3 = *(const bf16x8*)(zc + 32);
        float p0 = 0.f, p1 = 0.f, p2 = 0.f, p3 = 0.f;
        #pragma unroll
        for (int ct = 0; ct < 4; ++ct) {
            f32x4 acc = {0.f, 0.f, 0.f, 0.f};
            acc = __builtin_amdgcn_mfma_f32_16x16x32_bf16(a0, bfrag[0][ct], acc, 0, 0, 0);
            acc = __builtin_amdgcn_mfma_f32_16x16x32_bf16(a1, bfrag[1][ct], acc, 0, 0, 0);
            acc = __builtin_amdgcn_mfma_f32_16x16x32_bf16(a2, bfrag[2][ct], acc, 0, 0, 0);
            acc = __builtin_amdgcn_mfma_f32_16x16x32_bf16(a3, bfrag[3][ct], acc, 0, 0, 0);
            float h0 = fmaxf(acc[0] + b1r[ct], 0.f);
            float h1 = fmaxf(acc[1] + b1r[ct], 0.f);
            float h2 = fmaxf(acc[2] + b1r[ct], 0.f);
            float h3 = fmaxf(acc[3] + b1r[ct], 0.f);
            p0 = fmaf(h0, w2r[ct], p0);
            p1 = fmaf(h1, w2r[ct], p1);
            p2 = fmaf(h2, w2r[ct], p2);
            p3 = fmaf(h3, w2r[ct], p3);
        }
        #pragma unroll
        for (int m = 1; m < 16; m <<= 1) {
            p0 += __shfl_xor(p0, m, 64);
            p1 += __shfl_xor(p1, m, 64);
            p2 += __shfl_xor(p2, m, 64);
            p3 += __shfl_xor(p3, m, 64);
        }
        if (lr == 0) {
            int er = wbase + lg * 4;
            if (er + 0 < EV) out[er + 0] = 1.f / (1.f + expf(-(p0 + b2v)));
            if (er + 1 < EV) out[er + 1] = 1.f / (1.f + expf(-(p1 + b2v)));
            if (er + 2 < EV) out[er + 2] = 1.f / (1.f + expf(-(p2 + b2v)));
            if (er + 3 < EV) out[er + 3] = 1.f / (1.f + expf(-(p3 + b2v)));
        }
    }
}

extern "C" void kernel_launch(void* const* d_in, const int* in_sizes, int n_in,
                              void* d_out, int out_size, void* d_ws, size_t ws_size,
                              hipStream_t stream) {
    const float* x   = (const float*)d_in[0];
    const int* eidx  = (const int*)d_in[1];
    const int* evidx = (const int*)d_in[2];
    const float* W1  = (const float*)d_in[3];
    const float* b1  = (const float*)d_in[4];
    const float* W2  = (const float*)d_in[5];
    const float* b2  = (const float*)d_in[6];
    const float* Wf1 = (const float*)d_in[7];
    const float* bf1 = (const float*)d_in[8];
    const float* Wf2 = (const float*)d_in[9];
    const float* bf2 = (const float*)d_in[10];
    const int E  = in_sizes[1] / 2;
    const int EV = in_sizes[2] / 2;
    const int N  = in_sizes[0] / D_IN;
    const int* esrc = eidx;
    const int* edst = eidx + E;
    const int* es = evidx;
    const int* ed = evidx + EV;
    float* out = (float*)d_out;

    // workspace layout (bytes, total ~47 MB):
    //   di      @ 0     : N f32
    //   degi    @ 256K  : N i32
    //   rowptr  @ 512K  : (N+1) i32
    //   cursor  @ 768K  : N i32
    //   csr_src @ 1M    : E i32 (6.4 MB)
    //   hlinb   @ 8M    : N*128 bf16 (12.8 MB)  [conv1; region reused by hlin2b+zb]
    //   hbuf    @ 21M   : N*128 f32 (25.6 MB)   [conv1 output h, gemm2 input]
    char* ws = (char*)d_ws;
    float* di     = (float*)(ws);
    int*   degi   = (int*)(ws + (256 << 10));
    int*   rowptr = (int*)(ws + (512 << 10));
    int*   cursor = (int*)(ws + (768 << 10));
    int*   csrsrc = (int*)(ws + (1 << 20));
    short* hlinb  = (short*)(ws + ((size_t)8 << 20));
    short* hlin2b = (short*)(ws + ((size_t)8 << 20));                       // reuse (hlinb dead)
    short* zb     = (short*)(ws + ((size_t)8 << 20) + (size_t)N * 64 * 2);  // next 6.4 MB
    float* hbuf   = (float*)(ws + ((size_t)21 << 20));

    // ---- CSR build (once, reused by both convs) ----
    hipMemsetAsync(degi, 0, (size_t)N * sizeof(int), stream);
    degree_kernel<<<(E + 255) / 256, 256, 0, stream>>>(edst, E, degi);
    scan_kernel<<<1, 1024, 0, stream>>>(degi, rowptr, cursor, N);
    rsqrt_kernel<<<(N + 255) / 256, 256, 0, stream>>>(degi, di, N);
    fill_csr_kernel<<<(E + 255) / 256, 256, 0, stream>>>(esrc, edst, cursor, csrsrc, E);

    // ---- conv1: hlinb = bf16(x@W1) ; agg+selfloop+b1+relu -> h (f32) ----
    gemm_bf16out<64, 128, 64, 8, 4><<<(N + 63) / 64, 256, 0, stream>>>(x, W1, hlinb, N, D_IN);
    agg_kernel<128, true, false><<<(N + 3) / 4, 256, 0, stream>>>(
        hlinb, rowptr, csrsrc, di, b1, hbuf, nullptr, N);

    // ---- conv2: hlin2b = bf16(h@W2) ; agg+selfloop+b2 -> z (bf16) ----
    gemm_bf16out<64, 64, 64, 4, 4><<<(N + 63) / 64, 256, 0, stream>>>(hbuf, W2, hlin2b, N, D_H);
    agg_kernel<64, false, true><<<(N + 3) / 4, 256, 0, stream>>>(
        hlin2b, rowptr, csrsrc, di, b2, nullptr, zb, N);

    // ---- eval: MFMA MLP + sigmoid ----
    eval_mfma_kernel<<<(EV + 1023) / 1024, 256, 0, stream>>>(
        zb, es, ed, Wf1, bf1, Wf2, bf2, out, EV);
}

// Round 6
// 644.257 us; speedup vs baseline: 7.2353x; 1.1823x over previous
//
#include <hip/hip_runtime.h>
#include <hip/hip_bf16.h>
#include <math.h>

#define D_IN 256
#define D_H 128
#define D_L 64

typedef __attribute__((ext_vector_type(8))) short bf16x8;
typedef __attribute__((ext_vector_type(4))) float f32x4;

__device__ __forceinline__ short f2bs(float f) {
    __hip_bfloat16 b = __float2bfloat16(f);
    return *reinterpret_cast<short*>(&b);
}
__device__ __forceinline__ float bs2f_lo(unsigned v) { return __uint_as_float(v << 16); }
__device__ __forceinline__ float bs2f_hi(unsigned v) { return __uint_as_float(v & 0xffff0000u); }

// ---------------- degree (int histogram) ----------------
__global__ __launch_bounds__(256) void degree_kernel(const int* __restrict__ dst, int E,
                                                     int* __restrict__ degi) {
    int e = blockIdx.x * 256 + threadIdx.x;
    if (e < E) atomicAdd(&degi[dst[e]], 1);
}

__global__ __launch_bounds__(256) void rsqrt_kernel(const int* __restrict__ degi,
                                                    float* __restrict__ di, int n) {
    int i = blockIdx.x * 256 + threadIdx.x;
    if (i < n) di[i] = rsqrtf((float)degi[i] + 1.0f);
}

// ---------------- 3-phase hierarchical exclusive scan ----------------
// Phase A: per-block (1024-wide) exclusive scan of degi -> rowptr, block totals -> bsum
__global__ __launch_bounds__(1024) void scan_blk_kernel(const int* __restrict__ degi,
                                                        int* __restrict__ rowptr,
                                                        int* __restrict__ bsum, int n) {
    __shared__ int sums[1024];
    const int tid = threadIdx.x;
    const int gid = blockIdx.x * 1024 + tid;
    int v = (gid < n) ? degi[gid] : 0;
    sums[tid] = v;
    __syncthreads();
    #pragma unroll
    for (int off = 1; off < 1024; off <<= 1) {
        int t = (tid >= off) ? sums[tid - off] : 0;
        __syncthreads();
        sums[tid] += t;
        __syncthreads();
    }
    if (gid < n) rowptr[gid] = sums[tid] - v;   // exclusive within block
    if (tid == 1023) bsum[blockIdx.x] = sums[1023];
}

// Phase B: single wave inclusive scan of block totals (carry loop for nb > 64)
__global__ __launch_bounds__(64) void scan_sums_kernel(int* __restrict__ bsum, int nb) {
    const int lane = threadIdx.x & 63;
    int carry = 0;
    for (int base = 0; base < nb; base += 64) {
        int idx = base + lane;
        int v = (idx < nb) ? bsum[idx] : 0;
        #pragma unroll
        for (int off = 1; off < 64; off <<= 1) {
            int t = __shfl_up(v, off, 64);
            if (lane >= off) v += t;
        }
        if (idx < nb) bsum[idx] = v + carry;
        carry += __shfl(v, 63, 64);
    }
}

// Phase C: add block offsets, mirror into cursor, cap rowptr[n]
__global__ __launch_bounds__(256) void scan_add_kernel(int* __restrict__ rowptr,
                                                       const int* __restrict__ bsum,
                                                       int* __restrict__ cursor, int n, int E) {
    const int gid = blockIdx.x * 256 + threadIdx.x;
    if (gid < n) {
        int b = gid >> 10;
        int off = (b > 0) ? bsum[b - 1] : 0;
        int r = rowptr[gid] + off;
        rowptr[gid] = r;
        cursor[gid] = r;
    }
    if (gid == 0) rowptr[n] = E;
}

// ---------------- CSR fill: bucket src by dst ----------------
__global__ __launch_bounds__(256) void fill_csr_kernel(const int* __restrict__ src,
                                                       const int* __restrict__ dst,
                                                       int* __restrict__ cursor,
                                                       int* __restrict__ csr_src, int E) {
    int e = blockIdx.x * 256 + threadIdx.x;
    if (e < E) {
        int pos = atomicAdd(&cursor[dst[e]], 1);
        csr_src[pos] = src[e];
    }
}

// ---------------- tiled f32 GEMM, bf16 output: C[M,BN] = bf16(A[M,K] @ B[K,BN]) ----------------
template<int BM, int BN, int BK, int TM, int TN>
__global__ __launch_bounds__(256) void gemm_bf16out(const float* __restrict__ A,
                                                    const float* __restrict__ B,
                                                    short* __restrict__ C, int M, int K) {
    __shared__ float As[BK][BM + 1];
    __shared__ float Bs[BK][BN];
    constexpr int TX = BN / TN;
    constexpr int TY = BM / TM;
    static_assert(TX * TY == 256, "bad tile");
    const int tid = threadIdx.x;
    const int tx = tid % TX, ty = tid / TX;
    const int bm = blockIdx.x * BM;
    float acc[TM][TN] = {};
    for (int bk = 0; bk < K; bk += BK) {
        constexpr int A4 = BM * BK / (4 * 256);
        #pragma unroll
        for (int i = 0; i < A4; ++i) {
            int l = tid + i * 256;
            int r = l / (BK / 4);
            int kv = l % (BK / 4);
            int row = bm + r;
            float4 v = make_float4(0.f, 0.f, 0.f, 0.f);
            if (row < M) v = *(const float4*)&A[(size_t)row * K + bk + kv * 4];
            As[kv * 4 + 0][r] = v.x;
            As[kv * 4 + 1][r] = v.y;
            As[kv * 4 + 2][r] = v.z;
            As[kv * 4 + 3][r] = v.w;
        }
        constexpr int B4 = BK * BN / (4 * 256);
        #pragma unroll
        for (int i = 0; i < B4; ++i) {
            int l = tid + i * 256;
            int k = l / (BN / 4);
            int nv = l % (BN / 4);
            *(float4*)&Bs[k][nv * 4] = *(const float4*)&B[(size_t)(bk + k) * BN + nv * 4];
        }
        __syncthreads();
        #pragma unroll
        for (int k = 0; k < BK; ++k) {
            float a[TM], b[TN];
            #pragma unroll
            for (int i = 0; i < TM; ++i) a[i] = As[k][ty * TM + i];
            #pragma unroll
            for (int j = 0; j < TN; ++j) b[j] = Bs[k][tx * TN + j];
            #pragma unroll
            for (int i = 0; i < TM; ++i)
                #pragma unroll
                for (int j = 0; j < TN; ++j)
                    acc[i][j] = fmaf(a[i], b[j], acc[i][j]);
        }
        __syncthreads();
    }
    #pragma unroll
    for (int i = 0; i < TM; ++i) {
        int row = bm + ty * TM + i;
        if (row < M) {
            #pragma unroll
            for (int j = 0; j < TN; j += 4) {
                short4 o;
                o.x = f2bs(acc[i][j + 0]);
                o.y = f2bs(acc[i][j + 1]);
                o.z = f2bs(acc[i][j + 2]);
                o.w = f2bs(acc[i][j + 3]);
                *(short4*)&C[(size_t)row * BN + tx * TN + j] = o;
            }
        }
    }
}

// ---------------- CSR aggregation (bf16 gather, f32 accumulate), fused epilogue ----------------
template<int D, bool RELU, bool OUT_BF16>
__global__ __launch_bounds__(256) void agg_kernel(const short* __restrict__ hb,
                                                  const int* __restrict__ rowptr,
                                                  const int* __restrict__ csr_src,
                                                  const float* __restrict__ di,
                                                  const float* __restrict__ bias,
                                                  float* __restrict__ outf,
                                                  short* __restrict__ outb, int N) {
    const int wave = (blockIdx.x * 256 + threadIdx.x) >> 6;
    const int lane = threadIdx.x & 63;
    if (wave >= N) return;
    const int d = wave;
    const int start = rowptr[d], end = rowptr[d + 1];
    const float did = di[d];
    if constexpr (D == 128) {
        const unsigned* h2 = (const unsigned*)hb;   // 2 bf16 per word
        float ax = 0.f, ay = 0.f;
        for (int base = start; base < end; base += 64) {
            int idx = base + lane;
            bool valid = idx < end;
            int mys = valid ? csr_src[idx] : 0;
            float myc = valid ? di[mys] : 0.f;
            int cnt = min(64, end - base);
            for (int j = 0; j < cnt; ++j) {
                int s = __shfl(mys, j, 64);
                float coef = __shfl(myc, j, 64) * did;
                unsigned v = h2[(size_t)s * 64 + lane];
                ax = fmaf(bs2f_lo(v), coef, ax);
                ay = fmaf(bs2f_hi(v), coef, ay);
            }
        }
        float sl = did * did;
        unsigned hv = h2[(size_t)d * 64 + lane];
        float2 bv = ((const float2*)bias)[lane];
        float ox = ax + bs2f_lo(hv) * sl + bv.x;
        float oy = ay + bs2f_hi(hv) * sl + bv.y;
        if (RELU) { ox = fmaxf(ox, 0.f); oy = fmaxf(oy, 0.f); }
        if constexpr (OUT_BF16) {
            unsigned o = ((unsigned)(unsigned short)f2bs(oy) << 16) |
                         (unsigned)(unsigned short)f2bs(ox);
            ((unsigned*)outb)[(size_t)d * 64 + lane] = o;
        } else {
            ((float2*)outf)[(size_t)d * 64 + lane] = make_float2(ox, oy);
        }
    } else {
        const unsigned short* h1 = (const unsigned short*)hb;
        float acc = 0.f;
        for (int base = start; base < end; base += 64) {
            int idx = base + lane;
            bool valid = idx < end;
            int mys = valid ? csr_src[idx] : 0;
            float myc = valid ? di[mys] : 0.f;
            int cnt = min(64, end - base);
            for (int j = 0; j < cnt; ++j) {
                int s = __shfl(mys, j, 64);
                float coef = __shfl(myc, j, 64) * did;
                float hv = __uint_as_float(((unsigned)h1[(size_t)s * 64 + lane]) << 16);
                acc = fmaf(hv, coef, acc);
            }
        }
        float sl = did * did;
        float hd = __uint_as_float(((unsigned)h1[(size_t)d * 64 + lane]) << 16);
        float v = acc + hd * sl + bias[lane];
        if (RELU) v = fmaxf(v, 0.f);
        if constexpr (OUT_BF16) {
            outb[(size_t)d * 64 + lane] = f2bs(v);
        } else {
            outf[(size_t)d * 64 + lane] = v;
        }
    }
}

// ---------------- eval: gather z (bf16) + MFMA MLP + sigmoid ----------------
__global__ __launch_bounds__(256) void eval_mfma_kernel(const short* __restrict__ zb,
                                                        const int* __restrict__ es,
                                                        const int* __restrict__ ed,
                                                        const float* __restrict__ Wf1,
                                                        const float* __restrict__ bf1,
                                                        const float* __restrict__ Wf2,
                                                        const float* __restrict__ bf2,
                                                        float* __restrict__ out, int EV) {
    const int tid = threadIdx.x;
    const int w = tid >> 6;
    const int l = tid & 63;
    const int lr = l & 15;    // A-row / C-col index
    const int lg = l >> 4;    // k-group / C-row-group
    bf16x8 bfrag[4][4];       // [kk][ct]
    #pragma unroll
    for (int kk = 0; kk < 4; ++kk)
        #pragma unroll
        for (int ct = 0; ct < 4; ++ct) {
            bf16x8 t;
            #pragma unroll
            for (int j = 0; j < 8; ++j)
                t[j] = f2bs(Wf1[(size_t)(kk * 32 + lg * 8 + j) * 64 + ct * 16 + lr]);
            bfrag[kk][ct] = t;
        }
    float b1r[4], w2r[4];
    #pragma unroll
    for (int ct = 0; ct < 4; ++ct) {
        b1r[ct] = bf1[ct * 16 + lr];
        w2r[ct] = Wf2[ct * 16 + lr];
    }
    const float b2v = bf2[0];

    const int eb = blockIdx.x * 1024;
    for (int t = 0; t < 16; ++t) {
        const int wbase = eb + t * 64 + w * 16;
        int edge = wbase + lr;
        int ec = edge < EV ? edge : 0;
        int ns = es[ec], nd = ed[ec];
        const short* za = zb + (size_t)ns * 64 + lg * 8;
        const short* zc = zb + (size_t)nd * 64 + lg * 8;
        bf16x8 a0 = *(const bf16x8*)(za);
        bf16x8 a1 = *(const bf16x8*)(za + 32);
        bf16x8 a2 = *(const bf16x8*)(zc);
        bf16x8 a3 = *(const bf16x8*)(zc + 32);
        float p0 = 0.f, p1 = 0.f, p2 = 0.f, p3 = 0.f;
        #pragma unroll
        for (int ct = 0; ct < 4; ++ct) {
            f32x4 acc = {0.f, 0.f, 0.f, 0.f};
            acc = __builtin_amdgcn_mfma_f32_16x16x32_bf16(a0, bfrag[0][ct], acc, 0, 0, 0);
            acc = __builtin_amdgcn_mfma_f32_16x16x32_bf16(a1, bfrag[1][ct], acc, 0, 0, 0);
            acc = __builtin_amdgcn_mfma_f32_16x16x32_bf16(a2, bfrag[2][ct], acc, 0, 0, 0);
            acc = __builtin_amdgcn_mfma_f32_16x16x32_bf16(a3, bfrag[3][ct], acc, 0, 0, 0);
            float h0 = fmaxf(acc[0] + b1r[ct], 0.f);
            float h1 = fmaxf(acc[1] + b1r[ct], 0.f);
            float h2 = fmaxf(acc[2] + b1r[ct], 0.f);
            float h3 = fmaxf(acc[3] + b1r[ct], 0.f);
            p0 = fmaf(h0, w2r[ct], p0);
            p1 = fmaf(h1, w2r[ct], p1);
            p2 = fmaf(h2, w2r[ct], p2);
            p3 = fmaf(h3, w2r[ct], p3);
        }
        #pragma unroll
        for (int m = 1; m < 16; m <<= 1) {
            p0 += __shfl_xor(p0, m, 64);
            p1 += __shfl_xor(p1, m, 64);
            p2 += __shfl_xor(p2, m, 64);
            p3 += __shfl_xor(p3, m, 64);
        }
        if (lr == 0) {
            int er = wbase + lg * 4;
            if (er + 0 < EV) out[er + 0] = 1.f / (1.f + expf(-(p0 + b2v)));
            if (er + 1 < EV) out[er + 1] = 1.f / (1.f + expf(-(p1 + b2v)));
            if (er + 2 < EV) out[er + 2] = 1.f / (1.f + expf(-(p2 + b2v)));
            if (er + 3 < EV) out[er + 3] = 1.f / (1.f + expf(-(p3 + b2v)));
        }
    }
}

extern "C" void kernel_launch(void* const* d_in, const int* in_sizes, int n_in,
                              void* d_out, int out_size, void* d_ws, size_t ws_size,
                              hipStream_t stream) {
    const float* x   = (const float*)d_in[0];
    const int* eidx  = (const int*)d_in[1];
    const int* evidx = (const int*)d_in[2];
    const float* W1  = (const float*)d_in[3];
    const float* b1  = (const float*)d_in[4];
    const float* W2  = (const float*)d_in[5];
    const float* b2  = (const float*)d_in[6];
    const float* Wf1 = (const float*)d_in[7];
    const float* bf1 = (const float*)d_in[8];
    const float* Wf2 = (const float*)d_in[9];
    const float* bf2 = (const float*)d_in[10];
    const int E  = in_sizes[1] / 2;
    const int EV = in_sizes[2] / 2;
    const int N  = in_sizes[0] / D_IN;
    const int* esrc = eidx;
    const int* edst = eidx + E;
    const int* es = evidx;
    const int* ed = evidx + EV;
    float* out = (float*)d_out;

    // workspace layout (bytes, total ~47 MB):
    //   di      @ 0      : N f32
    //   degi    @ 256K   : N i32
    //   rowptr  @ 512K   : (N+1) i32
    //   cursor  @ 768K   : N i32           (ends ~963K)
    //   bsum    @ 1000K  : ceil(N/1024) i32
    //   csr_src @ 1M     : E i32 (6.4 MB)
    //   hlinb   @ 8M     : N*128 bf16 (12.8 MB)  [conv1; region reused by hlin2b+zb]
    //   hbuf    @ 21M    : N*128 f32 (25.6 MB)
    char* ws = (char*)d_ws;
    float* di     = (float*)(ws);
    int*   degi   = (int*)(ws + (256 << 10));
    int*   rowptr = (int*)(ws + (512 << 10));
    int*   cursor = (int*)(ws + (768 << 10));
    int*   bsum   = (int*)(ws + (1000 << 10));
    int*   csrsrc = (int*)(ws + (1 << 20));
    short* hlinb  = (short*)(ws + ((size_t)8 << 20));
    short* hlin2b = (short*)(ws + ((size_t)8 << 20));                       // reuse (hlinb dead)
    short* zb     = (short*)(ws + ((size_t)8 << 20) + (size_t)N * 64 * 2);  // next 6.4 MB
    float* hbuf   = (float*)(ws + ((size_t)21 << 20));

    const int NB = (N + 1023) / 1024;

    // ---- CSR build (once, reused by both convs) ----
    hipMemsetAsync(degi, 0, (size_t)N * sizeof(int), stream);
    degree_kernel<<<(E + 255) / 256, 256, 0, stream>>>(edst, E, degi);
    scan_blk_kernel<<<NB, 1024, 0, stream>>>(degi, rowptr, bsum, N);
    scan_sums_kernel<<<1, 64, 0, stream>>>(bsum, NB);
    scan_add_kernel<<<(N + 255) / 256, 256, 0, stream>>>(rowptr, bsum, cursor, N, E);
    rsqrt_kernel<<<(N + 255) / 256, 256, 0, stream>>>(degi, di, N);
    fill_csr_kernel<<<(E + 255) / 256, 256, 0, stream>>>(esrc, edst, cursor, csrsrc, E);

    // ---- conv1: hlinb = bf16(x@W1) ; agg+selfloop+b1+relu -> h (f32) ----
    gemm_bf16out<64, 128, 64, 8, 4><<<(N + 63) / 64, 256, 0, stream>>>(x, W1, hlinb, N, D_IN);
    agg_kernel<128, true, false><<<(N + 3) / 4, 256, 0, stream>>>(
        hlinb, rowptr, csrsrc, di, b1, hbuf, nullptr, N);

    // ---- conv2: hlin2b = bf16(h@W2) ; agg+selfloop+b2 -> z (bf16) ----
    gemm_bf16out<64, 64, 64, 4, 4><<<(N + 63) / 64, 256, 0, stream>>>(hbuf, W2, hlin2b, N, D_H);
    agg_kernel<64, false, true><<<(N + 3) / 4, 256, 0, stream>>>(
        hlin2b, rowptr, csrsrc, di, b2, nullptr, zb, N);

    // ---- eval: MFMA MLP + sigmoid ----
    eval_mfma_kernel<<<(EV + 1023) / 1024, 256, 0, stream>>>(
        zb, es, ed, Wf1, bf1, Wf2, bf2, out, EV);
}

// Round 8
// 595.727 us; speedup vs baseline: 7.8247x; 1.0815x over previous
//
#include <hip/hip_runtime.h>
#include <hip/hip_bf16.h>
#include <math.h>

#define D_IN 256
#define D_H 128
#define D_L 64
#define NXCD 8

typedef __attribute__((ext_vector_type(8))) short bf16x8;
typedef __attribute__((ext_vector_type(4))) float f32x4;

__device__ __forceinline__ short f2bs(float f) {
    __hip_bfloat16 b = __float2bfloat16(f);
    return *reinterpret_cast<short*>(&b);
}
__device__ __forceinline__ float bs2f_lo(unsigned v) { return __uint_as_float(v << 16); }
__device__ __forceinline__ float bs2f_hi(unsigned v) { return __uint_as_float(v & 0xffff0000u); }

// ---------------- f32 -> bf16 elementwise (4/thread) ----------------
__global__ __launch_bounds__(256) void cvt_bf16_kernel(const float* __restrict__ in,
                                                       short* __restrict__ out, int n4) {
    int i = blockIdx.x * 256 + threadIdx.x;
    if (i < n4) {
        float4 v = ((const float4*)in)[i];
        short4 o;
        o.x = f2bs(v.x); o.y = f2bs(v.y); o.z = f2bs(v.z); o.w = f2bs(v.w);
        ((short4*)out)[i] = o;
    }
}

// ---------------- W[K][N] f32 -> WT[N][K] bf16 ----------------
__global__ __launch_bounds__(256) void cvt_wT_kernel(const float* __restrict__ W,
                                                     short* __restrict__ WT, int K, int N) {
    int t = blockIdx.x * 256 + threadIdx.x;
    if (t < K * N) {
        int k = t / N, n = t % N;
        WT[n * K + k] = f2bs(W[t]);
    }
}

// ---------------- degree, XCD-range-grouped ----------------
__global__ __launch_bounds__(256) void degree_x_kernel(const int* __restrict__ dst, int E,
                                                       int* __restrict__ degi, int npg) {
    const int grp = blockIdx.x & (NXCD - 1);
    const int nb = gridDim.x >> 3;
    const int bid = blockIdx.x >> 3;
    const int lo = grp * npg, hi = lo + npg;
    for (int e = bid * 256 + threadIdx.x; e < E; e += nb * 256) {
        int d = dst[e];
        if (d >= lo && d < hi) atomicAdd(&degi[d], 1);
    }
}

__global__ __launch_bounds__(256) void rsqrt_kernel(const int* __restrict__ degi,
                                                    float* __restrict__ di, int n) {
    int i = blockIdx.x * 256 + threadIdx.x;
    if (i < n) di[i] = rsqrtf((float)degi[i] + 1.0f);
}

// ---------------- 3-phase hierarchical exclusive scan ----------------
__global__ __launch_bounds__(1024) void scan_blk_kernel(const int* __restrict__ degi,
                                                        int* __restrict__ rowptr,
                                                        int* __restrict__ bsum, int n) {
    __shared__ int sums[1024];
    const int tid = threadIdx.x;
    const int gid = blockIdx.x * 1024 + tid;
    int v = (gid < n) ? degi[gid] : 0;
    sums[tid] = v;
    __syncthreads();
    #pragma unroll
    for (int off = 1; off < 1024; off <<= 1) {
        int t = (tid >= off) ? sums[tid - off] : 0;
        __syncthreads();
        sums[tid] += t;
        __syncthreads();
    }
    if (gid < n) rowptr[gid] = sums[tid] - v;
    if (tid == 1023) bsum[blockIdx.x] = sums[1023];
}

__global__ __launch_bounds__(64) void scan_sums_kernel(int* __restrict__ bsum, int nb) {
    const int lane = threadIdx.x & 63;
    int carry = 0;
    for (int base = 0; base < nb; base += 64) {
        int idx = base + lane;
        int v = (idx < nb) ? bsum[idx] : 0;
        #pragma unroll
        for (int off = 1; off < 64; off <<= 1) {
            int t = __shfl_up(v, off, 64);
            if (lane >= off) v += t;
        }
        if (idx < nb) bsum[idx] = v + carry;
        carry += __shfl(v, 63, 64);
    }
}

__global__ __launch_bounds__(256) void scan_add_kernel(int* __restrict__ rowptr,
                                                       const int* __restrict__ bsum,
                                                       int* __restrict__ cursor, int n, int E) {
    const int gid = blockIdx.x * 256 + threadIdx.x;
    if (gid < n) {
        int b = gid >> 10;
        int off = (b > 0) ? bsum[b - 1] : 0;
        int r = rowptr[gid] + off;
        rowptr[gid] = r;
        cursor[gid] = r;
    }
    if (gid == 0) rowptr[n] = E;
}

// ---------------- CSR fill, XCD-range-grouped ----------------
__global__ __launch_bounds__(256) void fill_csr_x_kernel(const int* __restrict__ src,
                                                         const int* __restrict__ dst,
                                                         int* __restrict__ cursor,
                                                         int* __restrict__ csr_src,
                                                         int E, int npg) {
    const int grp = blockIdx.x & (NXCD - 1);
    const int nb = gridDim.x >> 3;
    const int bid = blockIdx.x >> 3;
    const int lo = grp * npg, hi = lo + npg;
    for (int e = bid * 256 + threadIdx.x; e < E; e += nb * 256) {
        int d = dst[e];
        if (d >= lo && d < hi) {
            int pos = atomicAdd(&cursor[d], 1);
            csr_src[pos] = src[e];
        }
    }
}

// ---------------- MFMA GEMM: C[M,N]bf16 = A[M,K]bf16 @ BT[N,K]bf16 ----------------
// 256 thr = 4 waves in 2x2; per wave: 32 rows x N/2 cols. No LDS: A streamed
// (64B-aligned fully-used lines), BT is tiny & L2-hot.
template<int N, int K>
__global__ __launch_bounds__(256) void mfma_gemm_kernel(const short* __restrict__ A,
                                                        const short* __restrict__ BT,
                                                        short* __restrict__ C, int M) {
    const int tid = threadIdx.x;
    const int w = tid >> 6;
    const int l = tid & 63;
    const int lr = l & 15, lg = l >> 4;
    const int wr = w >> 1, wc = w & 1;
    const int bm = blockIdx.x * 64;
    constexpr int CT = (N / 2) / 16;
    f32x4 acc[2][CT] = {};
    const short* arow0 = A + (size_t)(bm + wr * 32 + lr) * K + lg * 8;
    const short* arow1 = arow0 + 16 * K;
    #pragma unroll
    for (int ks = 0; ks < K / 32; ++ks) {
        bf16x8 a0 = *(const bf16x8*)(arow0 + ks * 32);
        bf16x8 a1 = *(const bf16x8*)(arow1 + ks * 32);
        #pragma unroll
        for (int ct = 0; ct < CT; ++ct) {
            int col = wc * (N / 2) + ct * 16 + lr;
            bf16x8 b = *(const bf16x8*)(BT + (size_t)col * K + ks * 32 + lg * 8);
            acc[0][ct] = __builtin_amdgcn_mfma_f32_16x16x32_bf16(a0, b, acc[0][ct], 0, 0, 0);
            acc[1][ct] = __builtin_amdgcn_mfma_f32_16x16x32_bf16(a1, b, acc[1][ct], 0, 0, 0);
        }
    }
    #pragma unroll
    for (int i = 0; i < 2; ++i)
        #pragma unroll
        for (int ct = 0; ct < CT; ++ct)
            #pragma unroll
            for (int r = 0; r < 4; ++r) {
                int row = bm + wr * 32 + i * 16 + lg * 4 + r;
                int col = wc * (N / 2) + ct * 16 + lr;
                if (row < M) C[(size_t)row * N + col] = f2bs(acc[i][ct][r]);
            }
}

// ---------------- CSR aggregation (bf16 gather, f32 accumulate), fused epilogue ----------------
template<int D, bool RELU, bool OUT_BF16>
__global__ __launch_bounds__(256) void agg_kernel(const short* __restrict__ hb,
                                                  const int* __restrict__ rowptr,
                                                  const int* __restrict__ csr_src,
                                                  const float* __restrict__ di,
                                                  const float* __restrict__ bias,
                                                  float* __restrict__ outf,
                                                  short* __restrict__ outb, int N) {
    const int wave = (blockIdx.x * 256 + threadIdx.x) >> 6;
    const int lane = threadIdx.x & 63;
    if (wave >= N) return;
    const int d = wave;
    const int start = rowptr[d], end = rowptr[d + 1];
    const float did = di[d];
    if constexpr (D == 128) {
        const unsigned* h2 = (const unsigned*)hb;
        float ax = 0.f, ay = 0.f;
        for (int base = start; base < end; base += 64) {
            int idx = base + lane;
            bool valid = idx < end;
            int mys = valid ? csr_src[idx] : 0;
            float myc = valid ? di[mys] : 0.f;
            int cnt = min(64, end - base);
            for (int j = 0; j < cnt; ++j) {
                int s = __shfl(mys, j, 64);
                float coef = __shfl(myc, j, 64) * did;
                unsigned v = h2[(size_t)s * 64 + lane];
                ax = fmaf(bs2f_lo(v), coef, ax);
                ay = fmaf(bs2f_hi(v), coef, ay);
            }
        }
        float sl = did * did;
        unsigned hv = h2[(size_t)d * 64 + lane];
        float2 bv = ((const float2*)bias)[lane];
        float ox = ax + bs2f_lo(hv) * sl + bv.x;
        float oy = ay + bs2f_hi(hv) * sl + bv.y;
        if (RELU) { ox = fmaxf(ox, 0.f); oy = fmaxf(oy, 0.f); }
        if constexpr (OUT_BF16) {
            unsigned o = ((unsigned)(unsigned short)f2bs(oy) << 16) |
                         (unsigned)(unsigned short)f2bs(ox);
            ((unsigned*)outb)[(size_t)d * 64 + lane] = o;
        } else {
            ((float2*)outf)[(size_t)d * 64 + lane] = make_float2(ox, oy);
        }
    } else {
        const unsigned short* h1 = (const unsigned short*)hb;
        float acc = 0.f;
        for (int base = start; base < end; base += 64) {
            int idx = base + lane;
            bool valid = idx < end;
            int mys = valid ? csr_src[idx] : 0;
            float myc = valid ? di[mys] : 0.f;
            int cnt = min(64, end - base);
            for (int j = 0; j < cnt; ++j) {
                int s = __shfl(mys, j, 64);
                float coef = __shfl(myc, j, 64) * did;
                float hv = __uint_as_float(((unsigned)h1[(size_t)s * 64 + lane]) << 16);
                acc = fmaf(hv, coef, acc);
            }
        }
        float sl = did * did;
        float hd = __uint_as_float(((unsigned)h1[(size_t)d * 64 + lane]) << 16);
        float v = acc + hd * sl + bias[lane];
        if (RELU) v = fmaxf(v, 0.f);
        if constexpr (OUT_BF16) {
            outb[(size_t)d * 64 + lane] = f2bs(v);
        } else {
            outf[(size_t)d * 64 + lane] = v;
        }
    }
}

// ---------------- eval: gather z (bf16) + MFMA MLP + sigmoid ----------------
__global__ __launch_bounds__(256) void eval_mfma_kernel(const short* __restrict__ zb,
                                                        const int* __restrict__ es,
                                                        const int* __restrict__ ed,
                                                        const float* __restrict__ Wf1,
                                                        const float* __restrict__ bf1,
                                                        const float* __restrict__ Wf2,
                                                        const float* __restrict__ bf2,
                                                        float* __restrict__ out, int EV) {
    const int tid = threadIdx.x;
    const int w = tid >> 6;
    const int l = tid & 63;
    const int lr = l & 15;
    const int lg = l >> 4;
    bf16x8 bfrag[4][4];
    #pragma unroll
    for (int kk = 0; kk < 4; ++kk)
        #pragma unroll
        for (int ct = 0; ct < 4; ++ct) {
            bf16x8 t;
            #pragma unroll
            for (int j = 0; j < 8; ++j)
                t[j] = f2bs(Wf1[(size_t)(kk * 32 + lg * 8 + j) * 64 + ct * 16 + lr]);
            bfrag[kk][ct] = t;
        }
    float b1r[4], w2r[4];
    #pragma unroll
    for (int ct = 0; ct < 4; ++ct) {
        b1r[ct] = bf1[ct * 16 + lr];
        w2r[ct] = Wf2[ct * 16 + lr];
    }
    const float b2v = bf2[0];

    const int eb = blockIdx.x * 1024;
    for (int t = 0; t < 16; ++t) {
        const int wbase = eb + t * 64 + w * 16;
        int edge = wbase + lr;
        int ec = edge < EV ? edge : 0;
        int ns = es[ec], nd = ed[ec];
        const short* za = zb + (size_t)ns * 64 + lg * 8;
        const short* zc = zb + (size_t)nd * 64 + lg * 8;
        bf16x8 a0 = *(const bf16x8*)(za);
        bf16x8 a1 = *(const bf16x8*)(za + 32);
        bf16x8 a2 = *(const bf16x8*)(zc);
        bf16x8 a3 = *(const bf16x8*)(zc + 32);
        float p0 = 0.f, p1 = 0.f, p2 = 0.f, p3 = 0.f;
        #pragma unroll
        for (int ct = 0; ct < 4; ++ct) {
            f32x4 acc = {0.f, 0.f, 0.f, 0.f};
            acc = __builtin_amdgcn_mfma_f32_16x16x32_bf16(a0, bfrag[0][ct], acc, 0, 0, 0);
            acc = __builtin_amdgcn_mfma_f32_16x16x32_bf16(a1, bfrag[1][ct], acc, 0, 0, 0);
            acc = __builtin_amdgcn_mfma_f32_16x16x32_bf16(a2, bfrag[2][ct], acc, 0, 0, 0);
            acc = __builtin_amdgcn_mfma_f32_16x16x32_bf16(a3, bfrag[3][ct], acc, 0, 0, 0);
            float h0 = fmaxf(acc[0] + b1r[ct], 0.f);
            float h1 = fmaxf(acc[1] + b1r[ct], 0.f);
            float h2 = fmaxf(acc[2] + b1r[ct], 0.f);
            float h3 = fmaxf(acc[3] + b1r[ct], 0.f);
            p0 = fmaf(h0, w2r[ct], p0);
            p1 = fmaf(h1, w2r[ct], p1);
            p2 = fmaf(h2, w2r[ct], p2);
            p3 = fmaf(h3, w2r[ct], p3);
        }
        #pragma unroll
        for (int m = 1; m < 16; m <<= 1) {
            p0 += __shfl_xor(p0, m, 64);
            p1 += __shfl_xor(p1, m, 64);
            p2 += __shfl_xor(p2, m, 64);
            p3 += __shfl_xor(p3, m, 64);
        }
        if (lr == 0) {
            int er = wbase + lg * 4;
            if (er + 0 < EV) out[er + 0] = 1.f / (1.f + expf(-(p0 + b2v)));
            if (er + 1 < EV) out[er + 1] = 1.f / (1.f + expf(-(p1 + b2v)));
            if (er + 2 < EV) out[er + 2] = 1.f / (1.f + expf(-(p2 + b2v)));
            if (er + 3 < EV) out[er + 3] = 1.f / (1.f + expf(-(p3 + b2v)));
        }
    }
}

extern "C" void kernel_launch(void* const* d_in, const int* in_sizes, int n_in,
                              void* d_out, int out_size, void* d_ws, size_t ws_size,
                              hipStream_t stream) {
    const float* x   = (const float*)d_in[0];
    const int* eidx  = (const int*)d_in[1];
    const int* evidx = (const int*)d_in[2];
    const float* W1  = (const float*)d_in[3];
    const float* b1  = (const float*)d_in[4];
    const float* W2  = (const float*)d_in[5];
    const float* b2  = (const float*)d_in[6];
    const float* Wf1 = (const float*)d_in[7];
    const float* bf1 = (const float*)d_in[8];
    const float* Wf2 = (const float*)d_in[9];
    const float* bf2 = (const float*)d_in[10];
    const int E  = in_sizes[1] / 2;
    const int EV = in_sizes[2] / 2;
    const int N  = in_sizes[0] / D_IN;
    const int* esrc = eidx;
    const int* edst = eidx + E;
    const int* es = evidx;
    const int* ed = evidx + EV;
    float* out = (float*)d_out;

    // workspace layout (bytes, max used ~46.8 MB):
    //   di 0 | degi 256K | rowptr 512K | cursor 768K | bsum 1000K
    //   csr_src 1M..7.4M | Wb1T @7.5M (64K) | Wb2T @7.7M (16K)
    //   xb   8M..33.6M (bf16 x)            [dead after gemm1]
    //   hb   8M..20.8M (bf16 h, over xb)   [agg1 out, gemm2 in]
    //   hlin2b 21M..27.4M                  [gemm2 out, agg2 in]
    //   hlinb 34M..46.8M                   [gemm1 out, agg1 in]
    //   zb   40M..46.4M (over hlinb)       [agg2 out, eval in]
    char* ws = (char*)d_ws;
    float* di     = (float*)(ws);
    int*   degi   = (int*)(ws + (256 << 10));
    int*   rowptr = (int*)(ws + (512 << 10));
    int*   cursor = (int*)(ws + (768 << 10));
    int*   bsum   = (int*)(ws + (1000 << 10));
    int*   csrsrc = (int*)(ws + (1 << 20));
    short* Wb1T   = (short*)(ws + (size_t)7500 * 1024);
    short* Wb2T   = (short*)(ws + (size_t)7700 * 1024);
    short* xb     = (short*)(ws + ((size_t)8 << 20));
    short* hb     = (short*)(ws + ((size_t)8 << 20));    // reuse after xb dead
    short* hlin2b = (short*)(ws + ((size_t)21 << 20));
    short* hlinb  = (short*)(ws + ((size_t)34 << 20));
    short* zb     = (short*)(ws + ((size_t)40 << 20));

    const int NB = (N + 1023) / 1024;
    const int NPG = (N + NXCD - 1) / NXCD;   // 6250

    // ---- weight/feature bf16 prep ----
    cvt_bf16_kernel<<<(N * D_IN / 4 + 255) / 256, 256, 0, stream>>>(x, xb, N * D_IN / 4);
    cvt_wT_kernel<<<(D_IN * D_H + 255) / 256, 256, 0, stream>>>(W1, Wb1T, D_IN, D_H);
    cvt_wT_kernel<<<(D_H * D_L + 255) / 256, 256, 0, stream>>>(W2, Wb2T, D_H, D_L);

    // ---- CSR build (XCD-grouped) ----
    hipMemsetAsync(degi, 0, (size_t)N * sizeof(int), stream);
    degree_x_kernel<<<512, 256, 0, stream>>>(edst, E, degi, NPG);
    scan_blk_kernel<<<NB, 1024, 0, stream>>>(degi, rowptr, bsum, N);
    scan_sums_kernel<<<1, 64, 0, stream>>>(bsum, NB);
    scan_add_kernel<<<(N + 255) / 256, 256, 0, stream>>>(rowptr, bsum, cursor, N, E);
    rsqrt_kernel<<<(N + 255) / 256, 256, 0, stream>>>(degi, di, N);
    fill_csr_x_kernel<<<512, 256, 0, stream>>>(esrc, edst, cursor, csrsrc, E, NPG);

    // ---- conv1: hlinb = bf16(xb@W1) ; agg+selfloop+b1+relu -> hb (bf16) ----
    mfma_gemm_kernel<D_H, D_IN><<<(N + 63) / 64, 256, 0, stream>>>(xb, Wb1T, hlinb, N);
    agg_kernel<128, true, true><<<(N + 3) / 4, 256, 0, stream>>>(
        hlinb, rowptr, csrsrc, di, b1, nullptr, hb, N);

    // ---- conv2: hlin2b = bf16(hb@W2) ; agg+selfloop+b2 -> zb (bf16) ----
    mfma_gemm_kernel<D_L, D_H><<<(N + 63) / 64, 256, 0, stream>>>(hb, Wb2T, hlin2b, N);
    agg_kernel<64, false, true><<<(N + 3) / 4, 256, 0, stream>>>(
        hlin2b, rowptr, csrsrc, di, b2, nullptr, zb, N);

    // ---- eval: MFMA MLP + sigmoid ----
    eval_mfma_kernel<<<(EV + 1023) / 1024, 256, 0, stream>>>(
        zb, es, ed, Wf1, bf1, Wf2, bf2, out, EV);
}

// Round 9
// 497.392 us; speedup vs baseline: 9.3716x; 1.1977x over previous
//
#include <hip/hip_runtime.h>
#include <hip/hip_bf16.h>
#include <math.h>

#define D_IN 256
#define D_H 128
#define D_L 64
#define NXCD 8

typedef __attribute__((ext_vector_type(8))) short bf16x8;
typedef __attribute__((ext_vector_type(4))) float f32x4;

__device__ __forceinline__ short f2bs(float f) {
    __hip_bfloat16 b = __float2bfloat16(f);
    return *reinterpret_cast<short*>(&b);
}
__device__ __forceinline__ float bs2f_lo(unsigned v) { return __uint_as_float(v << 16); }
__device__ __forceinline__ float bs2f_hi(unsigned v) { return __uint_as_float(v & 0xffff0000u); }

// ---------------- f32 -> bf16 elementwise (4/thread) ----------------
__global__ __launch_bounds__(256) void cvt_bf16_kernel(const float* __restrict__ in,
                                                       short* __restrict__ out, int n4) {
    int i = blockIdx.x * 256 + threadIdx.x;
    if (i < n4) {
        float4 v = ((const float4*)in)[i];
        short4 o;
        o.x = f2bs(v.x); o.y = f2bs(v.y); o.z = f2bs(v.z); o.w = f2bs(v.w);
        ((short4*)out)[i] = o;
    }
}

// ---------------- W[K][N] f32 -> WT[N][K] bf16 ----------------
__global__ __launch_bounds__(256) void cvt_wT_kernel(const float* __restrict__ W,
                                                     short* __restrict__ WT, int K, int N) {
    int t = blockIdx.x * 256 + threadIdx.x;
    if (t < K * N) {
        int k = t / N, n = t % N;
        WT[n * K + k] = f2bs(W[t]);
    }
}

// ---------------- degree, XCD-range-grouped ----------------
__global__ __launch_bounds__(256) void degree_x_kernel(const int* __restrict__ dst, int E,
                                                       int* __restrict__ degi, int npg) {
    const int grp = blockIdx.x & (NXCD - 1);
    const int nb = gridDim.x >> 3;
    const int bid = blockIdx.x >> 3;
    const int lo = grp * npg, hi = lo + npg;
    for (int e = bid * 256 + threadIdx.x; e < E; e += nb * 256) {
        int d = dst[e];
        if (d >= lo && d < hi) atomicAdd(&degi[d], 1);
    }
}

__global__ __launch_bounds__(256) void rsqrt_kernel(const int* __restrict__ degi,
                                                    float* __restrict__ di, int n) {
    int i = blockIdx.x * 256 + threadIdx.x;
    if (i < n) di[i] = rsqrtf((float)degi[i] + 1.0f);
}

// ---------------- 3-phase hierarchical exclusive scan ----------------
__global__ __launch_bounds__(1024) void scan_blk_kernel(const int* __restrict__ degi,
                                                        int* __restrict__ rowptr,
                                                        int* __restrict__ bsum, int n) {
    __shared__ int sums[1024];
    const int tid = threadIdx.x;
    const int gid = blockIdx.x * 1024 + tid;
    int v = (gid < n) ? degi[gid] : 0;
    sums[tid] = v;
    __syncthreads();
    #pragma unroll
    for (int off = 1; off < 1024; off <<= 1) {
        int t = (tid >= off) ? sums[tid - off] : 0;
        __syncthreads();
        sums[tid] += t;
        __syncthreads();
    }
    if (gid < n) rowptr[gid] = sums[tid] - v;
    if (tid == 1023) bsum[blockIdx.x] = sums[1023];
}

__global__ __launch_bounds__(64) void scan_sums_kernel(int* __restrict__ bsum, int nb) {
    const int lane = threadIdx.x & 63;
    int carry = 0;
    for (int base = 0; base < nb; base += 64) {
        int idx = base + lane;
        int v = (idx < nb) ? bsum[idx] : 0;
        #pragma unroll
        for (int off = 1; off < 64; off <<= 1) {
            int t = __shfl_up(v, off, 64);
            if (lane >= off) v += t;
        }
        if (idx < nb) bsum[idx] = v + carry;
        carry += __shfl(v, 63, 64);
    }
}

__global__ __launch_bounds__(256) void scan_add_kernel(int* __restrict__ rowptr,
                                                       const int* __restrict__ bsum,
                                                       int* __restrict__ cursor, int n, int E) {
    const int gid = blockIdx.x * 256 + threadIdx.x;
    if (gid < n) {
        int b = gid >> 10;
        int off = (b > 0) ? bsum[b - 1] : 0;
        int r = rowptr[gid] + off;
        rowptr[gid] = r;
        cursor[gid] = r;
    }
    if (gid == 0) rowptr[n] = E;
}

// ---------------- CSR fill, XCD-range-grouped ----------------
__global__ __launch_bounds__(256) void fill_csr_x_kernel(const int* __restrict__ src,
                                                         const int* __restrict__ dst,
                                                         int* __restrict__ cursor,
                                                         int* __restrict__ csr_src,
                                                         int E, int npg) {
    const int grp = blockIdx.x & (NXCD - 1);
    const int nb = gridDim.x >> 3;
    const int bid = blockIdx.x >> 3;
    const int lo = grp * npg, hi = lo + npg;
    for (int e = bid * 256 + threadIdx.x; e < E; e += nb * 256) {
        int d = dst[e];
        if (d >= lo && d < hi) {
            int pos = atomicAdd(&cursor[d], 1);
            csr_src[pos] = src[e];
        }
    }
}

// ---------------- MFMA GEMM: C[M,N]bf16 = A[M,K]bf16 @ BT[N,K]bf16 ----------------
template<int N, int K>
__global__ __launch_bounds__(256) void mfma_gemm_kernel(const short* __restrict__ A,
                                                        const short* __restrict__ BT,
                                                        short* __restrict__ C, int M) {
    const int tid = threadIdx.x;
    const int w = tid >> 6;
    const int l = tid & 63;
    const int lr = l & 15, lg = l >> 4;
    const int wr = w >> 1, wc = w & 1;
    const int bm = blockIdx.x * 64;
    constexpr int CT = (N / 2) / 16;
    f32x4 acc[2][CT] = {};
    const short* arow0 = A + (size_t)(bm + wr * 32 + lr) * K + lg * 8;
    const short* arow1 = arow0 + 16 * K;
    #pragma unroll
    for (int ks = 0; ks < K / 32; ++ks) {
        bf16x8 a0 = *(const bf16x8*)(arow0 + ks * 32);
        bf16x8 a1 = *(const bf16x8*)(arow1 + ks * 32);
        #pragma unroll
        for (int ct = 0; ct < CT; ++ct) {
            int col = wc * (N / 2) + ct * 16 + lr;
            bf16x8 b = *(const bf16x8*)(BT + (size_t)col * K + ks * 32 + lg * 8);
            acc[0][ct] = __builtin_amdgcn_mfma_f32_16x16x32_bf16(a0, b, acc[0][ct], 0, 0, 0);
            acc[1][ct] = __builtin_amdgcn_mfma_f32_16x16x32_bf16(a1, b, acc[1][ct], 0, 0, 0);
        }
    }
    #pragma unroll
    for (int i = 0; i < 2; ++i)
        #pragma unroll
        for (int ct = 0; ct < CT; ++ct)
            #pragma unroll
            for (int r = 0; r < 4; ++r) {
                int row = bm + wr * 32 + i * 16 + lg * 4 + r;
                int col = wc * (N / 2) + ct * 16 + lr;
                if (row < M) C[(size_t)row * N + col] = f2bs(acc[i][ct][r]);
            }
}

// ---------------- CSR aggregation (bf16 gather, f32 accumulate), fused epilogue ----------------
// Latency fix vs r8: manual 8x unroll of the edge loop so 8 independent row-gathers
// are in flight before the consuming FMAs; dual accumulator pairs break the FMA chain;
// di[src]*did pre-multiplied per lane.
template<int D, bool RELU, bool OUT_BF16>
__global__ __launch_bounds__(256) void agg_kernel(const short* __restrict__ hb,
                                                  const int* __restrict__ rowptr,
                                                  const int* __restrict__ csr_src,
                                                  const float* __restrict__ di,
                                                  const float* __restrict__ bias,
                                                  float* __restrict__ outf,
                                                  short* __restrict__ outb, int N) {
    const int wave = (blockIdx.x * 256 + threadIdx.x) >> 6;
    const int lane = threadIdx.x & 63;
    if (wave >= N) return;
    const int d = wave;
    const int start = rowptr[d], end = rowptr[d + 1];
    const float did = di[d];
    if constexpr (D == 128) {
        const unsigned* h2 = (const unsigned*)hb;
        float ax = 0.f, ay = 0.f, bx = 0.f, by = 0.f;
        for (int base = start; base < end; base += 64) {
            int idx = base + lane;
            bool valid = idx < end;
            int mys = valid ? csr_src[idx] : 0;
            float myc = valid ? di[mys] * did : 0.f;
            int cnt = min(64, end - base);
            int j = 0;
            for (; j + 8 <= cnt; j += 8) {
                int s0 = __shfl(mys, j + 0, 64), s1 = __shfl(mys, j + 1, 64);
                int s2 = __shfl(mys, j + 2, 64), s3 = __shfl(mys, j + 3, 64);
                int s4 = __shfl(mys, j + 4, 64), s5 = __shfl(mys, j + 5, 64);
                int s6 = __shfl(mys, j + 6, 64), s7 = __shfl(mys, j + 7, 64);
                float c0 = __shfl(myc, j + 0, 64), c1 = __shfl(myc, j + 1, 64);
                float c2 = __shfl(myc, j + 2, 64), c3 = __shfl(myc, j + 3, 64);
                float c4 = __shfl(myc, j + 4, 64), c5 = __shfl(myc, j + 5, 64);
                float c6 = __shfl(myc, j + 6, 64), c7 = __shfl(myc, j + 7, 64);
                unsigned v0 = h2[(size_t)s0 * 64 + lane];
                unsigned v1 = h2[(size_t)s1 * 64 + lane];
                unsigned v2 = h2[(size_t)s2 * 64 + lane];
                unsigned v3 = h2[(size_t)s3 * 64 + lane];
                unsigned v4 = h2[(size_t)s4 * 64 + lane];
                unsigned v5 = h2[(size_t)s5 * 64 + lane];
                unsigned v6 = h2[(size_t)s6 * 64 + lane];
                unsigned v7 = h2[(size_t)s7 * 64 + lane];
                ax = fmaf(bs2f_lo(v0), c0, ax); ay = fmaf(bs2f_hi(v0), c0, ay);
                bx = fmaf(bs2f_lo(v1), c1, bx); by = fmaf(bs2f_hi(v1), c1, by);
                ax = fmaf(bs2f_lo(v2), c2, ax); ay = fmaf(bs2f_hi(v2), c2, ay);
                bx = fmaf(bs2f_lo(v3), c3, bx); by = fmaf(bs2f_hi(v3), c3, by);
                ax = fmaf(bs2f_lo(v4), c4, ax); ay = fmaf(bs2f_hi(v4), c4, ay);
                bx = fmaf(bs2f_lo(v5), c5, bx); by = fmaf(bs2f_hi(v5), c5, by);
                ax = fmaf(bs2f_lo(v6), c6, ax); ay = fmaf(bs2f_hi(v6), c6, ay);
                bx = fmaf(bs2f_lo(v7), c7, bx); by = fmaf(bs2f_hi(v7), c7, by);
            }
            for (; j < cnt; ++j) {
                int s = __shfl(mys, j, 64);
                float c = __shfl(myc, j, 64);
                unsigned v = h2[(size_t)s * 64 + lane];
                ax = fmaf(bs2f_lo(v), c, ax);
                ay = fmaf(bs2f_hi(v), c, ay);
            }
        }
        ax += bx; ay += by;
        float sl = did * did;
        unsigned hv = ((const unsigned*)hb)[(size_t)d * 64 + lane];
        float2 bv = ((const float2*)bias)[lane];
        float ox = ax + bs2f_lo(hv) * sl + bv.x;
        float oy = ay + bs2f_hi(hv) * sl + bv.y;
        if (RELU) { ox = fmaxf(ox, 0.f); oy = fmaxf(oy, 0.f); }
        if constexpr (OUT_BF16) {
            unsigned o = ((unsigned)(unsigned short)f2bs(oy) << 16) |
                         (unsigned)(unsigned short)f2bs(ox);
            ((unsigned*)outb)[(size_t)d * 64 + lane] = o;
        } else {
            ((float2*)outf)[(size_t)d * 64 + lane] = make_float2(ox, oy);
        }
    } else {
        const unsigned short* h1 = (const unsigned short*)hb;
        float a0 = 0.f, a1 = 0.f;
        for (int base = start; base < end; base += 64) {
            int idx = base + lane;
            bool valid = idx < end;
            int mys = valid ? csr_src[idx] : 0;
            float myc = valid ? di[mys] * did : 0.f;
            int cnt = min(64, end - base);
            int j = 0;
            for (; j + 8 <= cnt; j += 8) {
                int s0 = __shfl(mys, j + 0, 64), s1 = __shfl(mys, j + 1, 64);
                int s2 = __shfl(mys, j + 2, 64), s3 = __shfl(mys, j + 3, 64);
                int s4 = __shfl(mys, j + 4, 64), s5 = __shfl(mys, j + 5, 64);
                int s6 = __shfl(mys, j + 6, 64), s7 = __shfl(mys, j + 7, 64);
                float c0 = __shfl(myc, j + 0, 64), c1 = __shfl(myc, j + 1, 64);
                float c2 = __shfl(myc, j + 2, 64), c3 = __shfl(myc, j + 3, 64);
                float c4 = __shfl(myc, j + 4, 64), c5 = __shfl(myc, j + 5, 64);
                float c6 = __shfl(myc, j + 6, 64), c7 = __shfl(myc, j + 7, 64);
                unsigned short v0 = h1[(size_t)s0 * 64 + lane];
                unsigned short v1 = h1[(size_t)s1 * 64 + lane];
                unsigned short v2 = h1[(size_t)s2 * 64 + lane];
                unsigned short v3 = h1[(size_t)s3 * 64 + lane];
                unsigned short v4 = h1[(size_t)s4 * 64 + lane];
                unsigned short v5 = h1[(size_t)s5 * 64 + lane];
                unsigned short v6 = h1[(size_t)s6 * 64 + lane];
                unsigned short v7 = h1[(size_t)s7 * 64 + lane];
                a0 = fmaf(__uint_as_float((unsigned)v0 << 16), c0, a0);
                a1 = fmaf(__uint_as_float((unsigned)v1 << 16), c1, a1);
                a0 = fmaf(__uint_as_float((unsigned)v2 << 16), c2, a0);
                a1 = fmaf(__uint_as_float((unsigned)v3 << 16), c3, a1);
                a0 = fmaf(__uint_as_float((unsigned)v4 << 16), c4, a0);
                a1 = fmaf(__uint_as_float((unsigned)v5 << 16), c5, a1);
                a0 = fmaf(__uint_as_float((unsigned)v6 << 16), c6, a0);
                a1 = fmaf(__uint_as_float((unsigned)v7 << 16), c7, a1);
            }
            for (; j < cnt; ++j) {
                int s = __shfl(mys, j, 64);
                float c = __shfl(myc, j, 64);
                a0 = fmaf(__uint_as_float((unsigned)h1[(size_t)s * 64 + lane] << 16), c, a0);
            }
        }
        float acc = a0 + a1;
        float sl = did * did;
        float hd = __uint_as_float(((unsigned)h1[(size_t)d * 64 + lane]) << 16);
        float v = acc + hd * sl + bias[lane];
        if (RELU) v = fmaxf(v, 0.f);
        if constexpr (OUT_BF16) {
            outb[(size_t)d * 64 + lane] = f2bs(v);
        } else {
            outf[(size_t)d * 64 + lane] = v;
        }
    }
}

// ---------------- eval: gather z (bf16) + MFMA MLP + sigmoid ----------------
__global__ __launch_bounds__(256) void eval_mfma_kernel(const short* __restrict__ zb,
                                                        const int* __restrict__ es,
                                                        const int* __restrict__ ed,
                                                        const float* __restrict__ Wf1,
                                                        const float* __restrict__ bf1,
                                                        const float* __restrict__ Wf2,
                                                        const float* __restrict__ bf2,
                                                        float* __restrict__ out, int EV) {
    const int tid = threadIdx.x;
    const int w = tid >> 6;
    const int l = tid & 63;
    const int lr = l & 15;
    const int lg = l >> 4;
    bf16x8 bfrag[4][4];
    #pragma unroll
    for (int kk = 0; kk < 4; ++kk)
        #pragma unroll
        for (int ct = 0; ct < 4; ++ct) {
            bf16x8 t;
            #pragma unroll
            for (int j = 0; j < 8; ++j)
                t[j] = f2bs(Wf1[(size_t)(kk * 32 + lg * 8 + j) * 64 + ct * 16 + lr]);
            bfrag[kk][ct] = t;
        }
    float b1r[4], w2r[4];
    #pragma unroll
    for (int ct = 0; ct < 4; ++ct) {
        b1r[ct] = bf1[ct * 16 + lr];
        w2r[ct] = Wf2[ct * 16 + lr];
    }
    const float b2v = bf2[0];

    const int eb = blockIdx.x * 1024;
    for (int t = 0; t < 16; ++t) {
        const int wbase = eb + t * 64 + w * 16;
        int edge = wbase + lr;
        int ec = edge < EV ? edge : 0;
        int ns = es[ec], nd = ed[ec];
        const short* za = zb + (size_t)ns * 64 + lg * 8;
        const short* zc = zb + (size_t)nd * 64 + lg * 8;
        bf16x8 a0 = *(const bf16x8*)(za);
        bf16x8 a1 = *(const bf16x8*)(za + 32);
        bf16x8 a2 = *(const bf16x8*)(zc);
        bf16x8 a3 = *(const bf16x8*)(zc + 32);
        float p0 = 0.f, p1 = 0.f, p2 = 0.f, p3 = 0.f;
        #pragma unroll
        for (int ct = 0; ct < 4; ++ct) {
            f32x4 acc = {0.f, 0.f, 0.f, 0.f};
            acc = __builtin_amdgcn_mfma_f32_16x16x32_bf16(a0, bfrag[0][ct], acc, 0, 0, 0);
            acc = __builtin_amdgcn_mfma_f32_16x16x32_bf16(a1, bfrag[1][ct], acc, 0, 0, 0);
            acc = __builtin_amdgcn_mfma_f32_16x16x32_bf16(a2, bfrag[2][ct], acc, 0, 0, 0);
            acc = __builtin_amdgcn_mfma_f32_16x16x32_bf16(a3, bfrag[3][ct], acc, 0, 0, 0);
            float h0 = fmaxf(acc[0] + b1r[ct], 0.f);
            float h1 = fmaxf(acc[1] + b1r[ct], 0.f);
            float h2 = fmaxf(acc[2] + b1r[ct], 0.f);
            float h3 = fmaxf(acc[3] + b1r[ct], 0.f);
            p0 = fmaf(h0, w2r[ct], p0);
            p1 = fmaf(h1, w2r[ct], p1);
            p2 = fmaf(h2, w2r[ct], p2);
            p3 = fmaf(h3, w2r[ct], p3);
        }
        #pragma unroll
        for (int m = 1; m < 16; m <<= 1) {
            p0 += __shfl_xor(p0, m, 64);
            p1 += __shfl_xor(p1, m, 64);
            p2 += __shfl_xor(p2, m, 64);
            p3 += __shfl_xor(p3, m, 64);
        }
        if (lr == 0) {
            int er = wbase + lg * 4;
            if (er + 0 < EV) out[er + 0] = 1.f / (1.f + expf(-(p0 + b2v)));
            if (er + 1 < EV) out[er + 1] = 1.f / (1.f + expf(-(p1 + b2v)));
            if (er + 2 < EV) out[er + 2] = 1.f / (1.f + expf(-(p2 + b2v)));
            if (er + 3 < EV) out[er + 3] = 1.f / (1.f + expf(-(p3 + b2v)));
        }
    }
}

extern "C" void kernel_launch(void* const* d_in, const int* in_sizes, int n_in,
                              void* d_out, int out_size, void* d_ws, size_t ws_size,
                              hipStream_t stream) {
    const float* x   = (const float*)d_in[0];
    const int* eidx  = (const int*)d_in[1];
    const int* evidx = (const int*)d_in[2];
    const float* W1  = (const float*)d_in[3];
    const float* b1  = (const float*)d_in[4];
    const float* W2  = (const float*)d_in[5];
    const float* b2  = (const float*)d_in[6];
    const float* Wf1 = (const float*)d_in[7];
    const float* bf1 = (const float*)d_in[8];
    const float* Wf2 = (const float*)d_in[9];
    const float* bf2 = (const float*)d_in[10];
    const int E  = in_sizes[1] / 2;
    const int EV = in_sizes[2] / 2;
    const int N  = in_sizes[0] / D_IN;
    const int* esrc = eidx;
    const int* edst = eidx + E;
    const int* es = evidx;
    const int* ed = evidx + EV;
    float* out = (float*)d_out;

    // workspace layout (bytes, max used ~46.8 MB):
    //   di 0 | degi 256K | rowptr 512K | cursor 768K | bsum 1000K
    //   csr_src 1M..7.4M | Wb1T @7.5M (64K) | Wb2T @7.7M (16K)
    //   xb   8M..33.6M (bf16 x)            [dead after gemm1]
    //   hb   8M..20.8M (bf16 h, over xb)   [agg1 out, gemm2 in]
    //   hlin2b 21M..27.4M                  [gemm2 out, agg2 in]
    //   hlinb 34M..46.8M                   [gemm1 out, agg1 in]
    //   zb   40M..46.4M (over hlinb)       [agg2 out, eval in]
    char* ws = (char*)d_ws;
    float* di     = (float*)(ws);
    int*   degi   = (int*)(ws + (256 << 10));
    int*   rowptr = (int*)(ws + (512 << 10));
    int*   cursor = (int*)(ws + (768 << 10));
    int*   bsum   = (int*)(ws + (1000 << 10));
    int*   csrsrc = (int*)(ws + (1 << 20));
    short* Wb1T   = (short*)(ws + (size_t)7500 * 1024);
    short* Wb2T   = (short*)(ws + (size_t)7700 * 1024);
    short* xb     = (short*)(ws + ((size_t)8 << 20));
    short* hb     = (short*)(ws + ((size_t)8 << 20));    // reuse after xb dead
    short* hlin2b = (short*)(ws + ((size_t)21 << 20));
    short* hlinb  = (short*)(ws + ((size_t)34 << 20));
    short* zb     = (short*)(ws + ((size_t)40 << 20));

    const int NB = (N + 1023) / 1024;
    const int NPG = (N + NXCD - 1) / NXCD;   // 6250

    // ---- weight/feature bf16 prep ----
    cvt_bf16_kernel<<<(N * D_IN / 4 + 255) / 256, 256, 0, stream>>>(x, xb, N * D_IN / 4);
    cvt_wT_kernel<<<(D_IN * D_H + 255) / 256, 256, 0, stream>>>(W1, Wb1T, D_IN, D_H);
    cvt_wT_kernel<<<(D_H * D_L + 255) / 256, 256, 0, stream>>>(W2, Wb2T, D_H, D_L);

    // ---- CSR build (XCD-grouped) ----
    hipMemsetAsync(degi, 0, (size_t)N * sizeof(int), stream);
    degree_x_kernel<<<512, 256, 0, stream>>>(edst, E, degi, NPG);
    scan_blk_kernel<<<NB, 1024, 0, stream>>>(degi, rowptr, bsum, N);
    scan_sums_kernel<<<1, 64, 0, stream>>>(bsum, NB);
    scan_add_kernel<<<(N + 255) / 256, 256, 0, stream>>>(rowptr, bsum, cursor, N, E);
    rsqrt_kernel<<<(N + 255) / 256, 256, 0, stream>>>(degi, di, N);
    fill_csr_x_kernel<<<512, 256, 0, stream>>>(esrc, edst, cursor, csrsrc, E, NPG);

    // ---- conv1: hlinb = bf16(xb@W1) ; agg+selfloop+b1+relu -> hb (bf16) ----
    mfma_gemm_kernel<D_H, D_IN><<<(N + 63) / 64, 256, 0, stream>>>(xb, Wb1T, hlinb, N);
    agg_kernel<128, true, true><<<(N + 3) / 4, 256, 0, stream>>>(
        hlinb, rowptr, csrsrc, di, b1, nullptr, hb, N);

    // ---- conv2: hlin2b = bf16(hb@W2) ; agg+selfloop+b2 -> zb (bf16) ----
    mfma_gemm_kernel<D_L, D_H><<<(N + 63) / 64, 256, 0, stream>>>(hb, Wb2T, hlin2b, N);
    agg_kernel<64, false, true><<<(N + 3) / 4, 256, 0, stream>>>(
        hlin2b, rowptr, csrsrc, di, b2, nullptr, zb, N);

    // ---- eval: MFMA MLP + sigmoid ----
    eval_mfma_kernel<<<(EV + 1023) / 1024, 256, 0, stream>>>(
        zb, es, ed, Wf1, bf1, Wf2, bf2, out, EV);
}

// Round 10
// 484.298 us; speedup vs baseline: 9.6250x; 1.0270x over previous
//
#include <hip/hip_runtime.h>
#include <hip/hip_bf16.h>
#include <math.h>

#define D_IN 256
#define D_H 128
#define D_L 64
#define NXCD 8

typedef __attribute__((ext_vector_type(8))) short bf16x8;
typedef __attribute__((ext_vector_type(4))) float f32x4;

__device__ __forceinline__ short f2bs(float f) {
    __hip_bfloat16 b = __float2bfloat16(f);
    return *reinterpret_cast<short*>(&b);
}
__device__ __forceinline__ float bs2f_lo(unsigned v) { return __uint_as_float(v << 16); }
__device__ __forceinline__ float bs2f_hi(unsigned v) { return __uint_as_float(v & 0xffff0000u); }

// ---------------- f32 -> bf16 elementwise (4/thread) ----------------
__global__ __launch_bounds__(256) void cvt_bf16_kernel(const float* __restrict__ in,
                                                       short* __restrict__ out, int n4) {
    int i = blockIdx.x * 256 + threadIdx.x;
    if (i < n4) {
        float4 v = ((const float4*)in)[i];
        short4 o;
        o.x = f2bs(v.x); o.y = f2bs(v.y); o.z = f2bs(v.z); o.w = f2bs(v.w);
        ((short4*)out)[i] = o;
    }
}

// ---------------- W[K][N] f32 -> WT[N][K] bf16 ----------------
__global__ __launch_bounds__(256) void cvt_wT_kernel(const float* __restrict__ W,
                                                     short* __restrict__ WT, int K, int N) {
    int t = blockIdx.x * 256 + threadIdx.x;
    if (t < K * N) {
        int k = t / N, n = t % N;
        WT[n * K + k] = f2bs(W[t]);
    }
}

// ---------------- degree: ungrouped, int4-vectorized, grid-stride ----------------
__global__ __launch_bounds__(256) void degree_v_kernel(const int* __restrict__ dst, int E,
                                                       int* __restrict__ degi) {
    const int nthr = gridDim.x * 256;
    const int tid = blockIdx.x * 256 + threadIdx.x;
    const int E4 = E >> 2;
    const int4* dst4 = (const int4*)dst;
    for (int i = tid; i < E4; i += nthr) {
        int4 d = dst4[i];
        atomicAdd(&degi[d.x], 1);
        atomicAdd(&degi[d.y], 1);
        atomicAdd(&degi[d.z], 1);
        atomicAdd(&degi[d.w], 1);
    }
    for (int e = E4 * 4 + tid; e < E; e += nthr) atomicAdd(&degi[dst[e]], 1);
}

__global__ __launch_bounds__(256) void rsqrt_kernel(const int* __restrict__ degi,
                                                    float* __restrict__ di, int n) {
    int i = blockIdx.x * 256 + threadIdx.x;
    if (i < n) di[i] = rsqrtf((float)degi[i] + 1.0f);
}

// ---------------- 3-phase hierarchical exclusive scan ----------------
__global__ __launch_bounds__(1024) void scan_blk_kernel(const int* __restrict__ degi,
                                                        int* __restrict__ rowptr,
                                                        int* __restrict__ bsum, int n) {
    __shared__ int sums[1024];
    const int tid = threadIdx.x;
    const int gid = blockIdx.x * 1024 + tid;
    int v = (gid < n) ? degi[gid] : 0;
    sums[tid] = v;
    __syncthreads();
    #pragma unroll
    for (int off = 1; off < 1024; off <<= 1) {
        int t = (tid >= off) ? sums[tid - off] : 0;
        __syncthreads();
        sums[tid] += t;
        __syncthreads();
    }
    if (gid < n) rowptr[gid] = sums[tid] - v;
    if (tid == 1023) bsum[blockIdx.x] = sums[1023];
}

__global__ __launch_bounds__(64) void scan_sums_kernel(int* __restrict__ bsum, int nb) {
    const int lane = threadIdx.x & 63;
    int carry = 0;
    for (int base = 0; base < nb; base += 64) {
        int idx = base + lane;
        int v = (idx < nb) ? bsum[idx] : 0;
        #pragma unroll
        for (int off = 1; off < 64; off <<= 1) {
            int t = __shfl_up(v, off, 64);
            if (lane >= off) v += t;
        }
        if (idx < nb) bsum[idx] = v + carry;
        carry += __shfl(v, 63, 64);
    }
}

__global__ __launch_bounds__(256) void scan_add_kernel(int* __restrict__ rowptr,
                                                       const int* __restrict__ bsum,
                                                       int* __restrict__ cursor, int n, int E) {
    const int gid = blockIdx.x * 256 + threadIdx.x;
    if (gid < n) {
        int b = gid >> 10;
        int off = (b > 0) ? bsum[b - 1] : 0;
        int r = rowptr[gid] + off;
        rowptr[gid] = r;
        cursor[gid] = r;
    }
    if (gid == 0) rowptr[n] = E;
}

// ---------------- CSR fill, XCD-range-grouped, int4-vectorized ----------------
__global__ __launch_bounds__(256) void fill_csr_x_kernel(const int* __restrict__ src,
                                                         const int* __restrict__ dst,
                                                         int* __restrict__ cursor,
                                                         int* __restrict__ csr_src,
                                                         int E, int npg) {
    const int grp = blockIdx.x & (NXCD - 1);
    const int nb = gridDim.x >> 3;
    const int bid = blockIdx.x >> 3;
    const int lo = grp * npg, hi = lo + npg;
    const int nthr = nb * 256;
    const int tid = bid * 256 + threadIdx.x;
    const int E4 = E >> 2;
    const int4* dst4 = (const int4*)dst;
    for (int i = tid; i < E4; i += nthr) {
        int4 d = dst4[i];
        int e = i * 4;
        if (d.x >= lo && d.x < hi) { int p = atomicAdd(&cursor[d.x], 1); csr_src[p] = src[e + 0]; }
        if (d.y >= lo && d.y < hi) { int p = atomicAdd(&cursor[d.y], 1); csr_src[p] = src[e + 1]; }
        if (d.z >= lo && d.z < hi) { int p = atomicAdd(&cursor[d.z], 1); csr_src[p] = src[e + 2]; }
        if (d.w >= lo && d.w < hi) { int p = atomicAdd(&cursor[d.w], 1); csr_src[p] = src[e + 3]; }
    }
    for (int e = E4 * 4 + tid; e < E; e += nthr) {
        int d = dst[e];
        if (d >= lo && d < hi) { int p = atomicAdd(&cursor[d], 1); csr_src[p] = src[e]; }
    }
}

// ---------------- MFMA GEMM: C[M,N]bf16 = A[M,K]bf16 @ BT[N,K]bf16 ----------------
template<int N, int K>
__global__ __launch_bounds__(256) void mfma_gemm_kernel(const short* __restrict__ A,
                                                        const short* __restrict__ BT,
                                                        short* __restrict__ C, int M) {
    const int tid = threadIdx.x;
    const int w = tid >> 6;
    const int l = tid & 63;
    const int lr = l & 15, lg = l >> 4;
    const int wr = w >> 1, wc = w & 1;
    const int bm = blockIdx.x * 64;
    constexpr int CT = (N / 2) / 16;
    f32x4 acc[2][CT] = {};
    const short* arow0 = A + (size_t)(bm + wr * 32 + lr) * K + lg * 8;
    const short* arow1 = arow0 + 16 * K;
    #pragma unroll
    for (int ks = 0; ks < K / 32; ++ks) {
        bf16x8 a0 = *(const bf16x8*)(arow0 + ks * 32);
        bf16x8 a1 = *(const bf16x8*)(arow1 + ks * 32);
        #pragma unroll
        for (int ct = 0; ct < CT; ++ct) {
            int col = wc * (N / 2) + ct * 16 + lr;
            bf16x8 b = *(const bf16x8*)(BT + (size_t)col * K + ks * 32 + lg * 8);
            acc[0][ct] = __builtin_amdgcn_mfma_f32_16x16x32_bf16(a0, b, acc[0][ct], 0, 0, 0);
            acc[1][ct] = __builtin_amdgcn_mfma_f32_16x16x32_bf16(a1, b, acc[1][ct], 0, 0, 0);
        }
    }
    #pragma unroll
    for (int i = 0; i < 2; ++i)
        #pragma unroll
        for (int ct = 0; ct < CT; ++ct)
            #pragma unroll
            for (int r = 0; r < 4; ++r) {
                int row = bm + wr * 32 + i * 16 + lg * 4 + r;
                int col = wc * (N / 2) + ct * 16 + lr;
                if (row < M) C[(size_t)row * N + col] = f2bs(acc[i][ct][r]);
            }
}

// ---------------- CSR aggregation (bf16 gather, f32 accumulate), 8x-unrolled ----------------
template<int D, bool RELU, bool OUT_BF16>
__global__ __launch_bounds__(256) void agg_kernel(const short* __restrict__ hb,
                                                  const int* __restrict__ rowptr,
                                                  const int* __restrict__ csr_src,
                                                  const float* __restrict__ di,
                                                  const float* __restrict__ bias,
                                                  float* __restrict__ outf,
                                                  short* __restrict__ outb, int N) {
    const int wave = (blockIdx.x * 256 + threadIdx.x) >> 6;
    const int lane = threadIdx.x & 63;
    if (wave >= N) return;
    const int d = wave;
    const int start = rowptr[d], end = rowptr[d + 1];
    const float did = di[d];
    if constexpr (D == 128) {
        const unsigned* h2 = (const unsigned*)hb;
        float ax = 0.f, ay = 0.f, bx = 0.f, by = 0.f;
        for (int base = start; base < end; base += 64) {
            int idx = base + lane;
            bool valid = idx < end;
            int mys = valid ? csr_src[idx] : 0;
            float myc = valid ? di[mys] * did : 0.f;
            int cnt = min(64, end - base);
            int j = 0;
            for (; j + 8 <= cnt; j += 8) {
                int s0 = __shfl(mys, j + 0, 64), s1 = __shfl(mys, j + 1, 64);
                int s2 = __shfl(mys, j + 2, 64), s3 = __shfl(mys, j + 3, 64);
                int s4 = __shfl(mys, j + 4, 64), s5 = __shfl(mys, j + 5, 64);
                int s6 = __shfl(mys, j + 6, 64), s7 = __shfl(mys, j + 7, 64);
                float c0 = __shfl(myc, j + 0, 64), c1 = __shfl(myc, j + 1, 64);
                float c2 = __shfl(myc, j + 2, 64), c3 = __shfl(myc, j + 3, 64);
                float c4 = __shfl(myc, j + 4, 64), c5 = __shfl(myc, j + 5, 64);
                float c6 = __shfl(myc, j + 6, 64), c7 = __shfl(myc, j + 7, 64);
                unsigned v0 = h2[(size_t)s0 * 64 + lane];
                unsigned v1 = h2[(size_t)s1 * 64 + lane];
                unsigned v2 = h2[(size_t)s2 * 64 + lane];
                unsigned v3 = h2[(size_t)s3 * 64 + lane];
                unsigned v4 = h2[(size_t)s4 * 64 + lane];
                unsigned v5 = h2[(size_t)s5 * 64 + lane];
                unsigned v6 = h2[(size_t)s6 * 64 + lane];
                unsigned v7 = h2[(size_t)s7 * 64 + lane];
                ax = fmaf(bs2f_lo(v0), c0, ax); ay = fmaf(bs2f_hi(v0), c0, ay);
                bx = fmaf(bs2f_lo(v1), c1, bx); by = fmaf(bs2f_hi(v1), c1, by);
                ax = fmaf(bs2f_lo(v2), c2, ax); ay = fmaf(bs2f_hi(v2), c2, ay);
                bx = fmaf(bs2f_lo(v3), c3, bx); by = fmaf(bs2f_hi(v3), c3, by);
                ax = fmaf(bs2f_lo(v4), c4, ax); ay = fmaf(bs2f_hi(v4), c4, ay);
                bx = fmaf(bs2f_lo(v5), c5, bx); by = fmaf(bs2f_hi(v5), c5, by);
                ax = fmaf(bs2f_lo(v6), c6, ax); ay = fmaf(bs2f_hi(v6), c6, ay);
                bx = fmaf(bs2f_lo(v7), c7, bx); by = fmaf(bs2f_hi(v7), c7, by);
            }
            for (; j < cnt; ++j) {
                int s = __shfl(mys, j, 64);
                float c = __shfl(myc, j, 64);
                unsigned v = h2[(size_t)s * 64 + lane];
                ax = fmaf(bs2f_lo(v), c, ax);
                ay = fmaf(bs2f_hi(v), c, ay);
            }
        }
        ax += bx; ay += by;
        float sl = did * did;
        unsigned hv = ((const unsigned*)hb)[(size_t)d * 64 + lane];
        float2 bv = ((const float2*)bias)[lane];
        float ox = ax + bs2f_lo(hv) * sl + bv.x;
        float oy = ay + bs2f_hi(hv) * sl + bv.y;
        if (RELU) { ox = fmaxf(ox, 0.f); oy = fmaxf(oy, 0.f); }
        if constexpr (OUT_BF16) {
            unsigned o = ((unsigned)(unsigned short)f2bs(oy) << 16) |
                         (unsigned)(unsigned short)f2bs(ox);
            ((unsigned*)outb)[(size_t)d * 64 + lane] = o;
        } else {
            ((float2*)outf)[(size_t)d * 64 + lane] = make_float2(ox, oy);
        }
    } else {
        const unsigned short* h1 = (const unsigned short*)hb;
        float a0 = 0.f, a1 = 0.f;
        for (int base = start; base < end; base += 64) {
            int idx = base + lane;
            bool valid = idx < end;
            int mys = valid ? csr_src[idx] : 0;
            float myc = valid ? di[mys] * did : 0.f;
            int cnt = min(64, end - base);
            int j = 0;
            for (; j + 8 <= cnt; j += 8) {
                int s0 = __shfl(mys, j + 0, 64), s1 = __shfl(mys, j + 1, 64);
                int s2 = __shfl(mys, j + 2, 64), s3 = __shfl(mys, j + 3, 64);
                int s4 = __shfl(mys, j + 4, 64), s5 = __shfl(mys, j + 5, 64);
                int s6 = __shfl(mys, j + 6, 64), s7 = __shfl(mys, j + 7, 64);
                float c0 = __shfl(myc, j + 0, 64), c1 = __shfl(myc, j + 1, 64);
                float c2 = __shfl(myc, j + 2, 64), c3 = __shfl(myc, j + 3, 64);
                float c4 = __shfl(myc, j + 4, 64), c5 = __shfl(myc, j + 5, 64);
                float c6 = __shfl(myc, j + 6, 64), c7 = __shfl(myc, j + 7, 64);
                unsigned short v0 = h1[(size_t)s0 * 64 + lane];
                unsigned short v1 = h1[(size_t)s1 * 64 + lane];
                unsigned short v2 = h1[(size_t)s2 * 64 + lane];
                unsigned short v3 = h1[(size_t)s3 * 64 + lane];
                unsigned short v4 = h1[(size_t)s4 * 64 + lane];
                unsigned short v5 = h1[(size_t)s5 * 64 + lane];
                unsigned short v6 = h1[(size_t)s6 * 64 + lane];
                unsigned short v7 = h1[(size_t)s7 * 64 + lane];
                a0 = fmaf(__uint_as_float((unsigned)v0 << 16), c0, a0);
                a1 = fmaf(__uint_as_float((unsigned)v1 << 16), c1, a1);
                a0 = fmaf(__uint_as_float((unsigned)v2 << 16), c2, a0);
                a1 = fmaf(__uint_as_float((unsigned)v3 << 16), c3, a1);
                a0 = fmaf(__uint_as_float((unsigned)v4 << 16), c4, a0);
                a1 = fmaf(__uint_as_float((unsigned)v5 << 16), c5, a1);
                a0 = fmaf(__uint_as_float((unsigned)v6 << 16), c6, a0);
                a1 = fmaf(__uint_as_float((unsigned)v7 << 16), c7, a1);
            }
            for (; j < cnt; ++j) {
                int s = __shfl(mys, j, 64);
                float c = __shfl(myc, j, 64);
                a0 = fmaf(__uint_as_float((unsigned)h1[(size_t)s * 64 + lane] << 16), c, a0);
            }
        }
        float acc = a0 + a1;
        float sl = did * did;
        float hd = __uint_as_float(((unsigned)h1[(size_t)d * 64 + lane]) << 16);
        float v = acc + hd * sl + bias[lane];
        if (RELU) v = fmaxf(v, 0.f);
        if constexpr (OUT_BF16) {
            outb[(size_t)d * 64 + lane] = f2bs(v);
        } else {
            outf[(size_t)d * 64 + lane] = v;
        }
    }
}

// ---------------- eval: gather z (bf16) + MFMA MLP + sigmoid ----------------
__global__ __launch_bounds__(256) void eval_mfma_kernel(const short* __restrict__ zb,
                                                        const int* __restrict__ es,
                                                        const int* __restrict__ ed,
                                                        const float* __restrict__ Wf1,
                                                        const float* __restrict__ bf1,
                                                        const float* __restrict__ Wf2,
                                                        const float* __restrict__ bf2,
                                                        float* __restrict__ out, int EV) {
    const int tid = threadIdx.x;
    const int w = tid >> 6;
    const int l = tid & 63;
    const int lr = l & 15;
    const int lg = l >> 4;
    bf16x8 bfrag[4][4];
    #pragma unroll
    for (int kk = 0; kk < 4; ++kk)
        #pragma unroll
        for (int ct = 0; ct < 4; ++ct) {
            bf16x8 t;
            #pragma unroll
            for (int j = 0; j < 8; ++j)
                t[j] = f2bs(Wf1[(size_t)(kk * 32 + lg * 8 + j) * 64 + ct * 16 + lr]);
            bfrag[kk][ct] = t;
        }
    float b1r[4], w2r[4];
    #pragma unroll
    for (int ct = 0; ct < 4; ++ct) {
        b1r[ct] = bf1[ct * 16 + lr];
        w2r[ct] = Wf2[ct * 16 + lr];
    }
    const float b2v = bf2[0];

    const int eb = blockIdx.x * 1024;
    for (int t = 0; t < 16; ++t) {
        const int wbase = eb + t * 64 + w * 16;
        int edge = wbase + lr;
        int ec = edge < EV ? edge : 0;
        int ns = es[ec], nd = ed[ec];
        const short* za = zb + (size_t)ns * 64 + lg * 8;
        const short* zc = zb + (size_t)nd * 64 + lg * 8;
        bf16x8 a0 = *(const bf16x8*)(za);
        bf16x8 a1 = *(const bf16x8*)(za + 32);
        bf16x8 a2 = *(const bf16x8*)(zc);
        bf16x8 a3 = *(const bf16x8*)(zc + 32);
        float p0 = 0.f, p1 = 0.f, p2 = 0.f, p3 = 0.f;
        #pragma unroll
        for (int ct = 0; ct < 4; ++ct) {
            f32x4 acc = {0.f, 0.f, 0.f, 0.f};
            acc = __builtin_amdgcn_mfma_f32_16x16x32_bf16(a0, bfrag[0][ct], acc, 0, 0, 0);
            acc = __builtin_amdgcn_mfma_f32_16x16x32_bf16(a1, bfrag[1][ct], acc, 0, 0, 0);
            acc = __builtin_amdgcn_mfma_f32_16x16x32_bf16(a2, bfrag[2][ct], acc, 0, 0, 0);
            acc = __builtin_amdgcn_mfma_f32_16x16x32_bf16(a3, bfrag[3][ct], acc, 0, 0, 0);
            float h0 = fmaxf(acc[0] + b1r[ct], 0.f);
            float h1 = fmaxf(acc[1] + b1r[ct], 0.f);
            float h2 = fmaxf(acc[2] + b1r[ct], 0.f);
            float h3 = fmaxf(acc[3] + b1r[ct], 0.f);
            p0 = fmaf(h0, w2r[ct], p0);
            p1 = fmaf(h1, w2r[ct], p1);
            p2 = fmaf(h2, w2r[ct], p2);
            p3 = fmaf(h3, w2r[ct], p3);
        }
        #pragma unroll
        for (int m = 1; m < 16; m <<= 1) {
            p0 += __shfl_xor(p0, m, 64);
            p1 += __shfl_xor(p1, m, 64);
            p2 += __shfl_xor(p2, m, 64);
            p3 += __shfl_xor(p3, m, 64);
        }
        if (lr == 0) {
            int er = wbase + lg * 4;
            if (er + 0 < EV) out[er + 0] = 1.f / (1.f + expf(-(p0 + b2v)));
            if (er + 1 < EV) out[er + 1] = 1.f / (1.f + expf(-(p1 + b2v)));
            if (er + 2 < EV) out[er + 2] = 1.f / (1.f + expf(-(p2 + b2v)));
            if (er + 3 < EV) out[er + 3] = 1.f / (1.f + expf(-(p3 + b2v)));
        }
    }
}

extern "C" void kernel_launch(void* const* d_in, const int* in_sizes, int n_in,
                              void* d_out, int out_size, void* d_ws, size_t ws_size,
                              hipStream_t stream) {
    const float* x   = (const float*)d_in[0];
    const int* eidx  = (const int*)d_in[1];
    const int* evidx = (const int*)d_in[2];
    const float* W1  = (const float*)d_in[3];
    const float* b1  = (const float*)d_in[4];
    const float* W2  = (const float*)d_in[5];
    const float* b2  = (const float*)d_in[6];
    const float* Wf1 = (const float*)d_in[7];
    const float* bf1 = (const float*)d_in[8];
    const float* Wf2 = (const float*)d_in[9];
    const float* bf2 = (const float*)d_in[10];
    const int E  = in_sizes[1] / 2;
    const int EV = in_sizes[2] / 2;
    const int N  = in_sizes[0] / D_IN;
    const int* esrc = eidx;
    const int* edst = eidx + E;
    const int* es = evidx;
    const int* ed = evidx + EV;
    float* out = (float*)d_out;

    // workspace layout (bytes, max used ~46.8 MB):
    //   di 0 | degi 256K | rowptr 512K | cursor 768K | bsum 1000K
    //   csr_src 1M..7.4M | Wb1T @7.5M (64K) | Wb2T @7.7M (16K)
    //   xb   8M..33.6M (bf16 x)            [dead after gemm1]
    //   hb   8M..20.8M (bf16 h, over xb)   [agg1 out, gemm2 in]
    //   hlin2b 21M..27.4M                  [gemm2 out, agg2 in]
    //   hlinb 34M..46.8M                   [gemm1 out, agg1 in]
    //   zb   40M..46.4M (over hlinb)       [agg2 out, eval in]
    char* ws = (char*)d_ws;
    float* di     = (float*)(ws);
    int*   degi   = (int*)(ws + (256 << 10));
    int*   rowptr = (int*)(ws + (512 << 10));
    int*   cursor = (int*)(ws + (768 << 10));
    int*   bsum   = (int*)(ws + (1000 << 10));
    int*   csrsrc = (int*)(ws + (1 << 20));
    short* Wb1T   = (short*)(ws + (size_t)7500 * 1024);
    short* Wb2T   = (short*)(ws + (size_t)7700 * 1024);
    short* xb     = (short*)(ws + ((size_t)8 << 20));
    short* hb     = (short*)(ws + ((size_t)8 << 20));    // reuse after xb dead
    short* hlin2b = (short*)(ws + ((size_t)21 << 20));
    short* hlinb  = (short*)(ws + ((size_t)34 << 20));
    short* zb     = (short*)(ws + ((size_t)40 << 20));

    const int NB = (N + 1023) / 1024;
    const int NPG = (N + NXCD - 1) / NXCD;   // 6250

    // ---- weight/feature bf16 prep ----
    cvt_bf16_kernel<<<(N * D_IN / 4 + 255) / 256, 256, 0, stream>>>(x, xb, N * D_IN / 4);
    cvt_wT_kernel<<<(D_IN * D_H + 255) / 256, 256, 0, stream>>>(W1, Wb1T, D_IN, D_H);
    cvt_wT_kernel<<<(D_H * D_L + 255) / 256, 256, 0, stream>>>(W2, Wb2T, D_H, D_L);

    // ---- CSR build ----
    hipMemsetAsync(degi, 0, (size_t)N * sizeof(int), stream);
    degree_v_kernel<<<2048, 256, 0, stream>>>(edst, E, degi);
    scan_blk_kernel<<<NB, 1024, 0, stream>>>(degi, rowptr, bsum, N);
    scan_sums_kernel<<<1, 64, 0, stream>>>(bsum, NB);
    scan_add_kernel<<<(N + 255) / 256, 256, 0, stream>>>(rowptr, bsum, cursor, N, E);
    rsqrt_kernel<<<(N + 255) / 256, 256, 0, stream>>>(degi, di, N);
    fill_csr_x_kernel<<<4096, 256, 0, stream>>>(esrc, edst, cursor, csrsrc, E, NPG);

    // ---- conv1: hlinb = bf16(xb@W1) ; agg+selfloop+b1+relu -> hb (bf16) ----
    mfma_gemm_kernel<D_H, D_IN><<<(N + 63) / 64, 256, 0, stream>>>(xb, Wb1T, hlinb, N);
    agg_kernel<128, true, true><<<(N + 3) / 4, 256, 0, stream>>>(
        hlinb, rowptr, csrsrc, di, b1, nullptr, hb, N);

    // ---- conv2: hlin2b = bf16(hb@W2) ; agg+selfloop+b2 -> zb (bf16) ----
    mfma_gemm_kernel<D_L, D_H><<<(N + 63) / 64, 256, 0, stream>>>(hb, Wb2T, hlin2b, N);
    agg_kernel<64, false, true><<<(N + 3) / 4, 256, 0, stream>>>(
        hlin2b, rowptr, csrsrc, di, b2, nullptr, zb, N);

    // ---- eval: MFMA MLP + sigmoid ----
    eval_mfma_kernel<<<(EV + 1023) / 1024, 256, 0, stream>>>(
        zb, es, ed, Wf1, bf1, Wf2, bf2, out, EV);
}

// Round 11
// 455.112 us; speedup vs baseline: 10.2422x; 1.0641x over previous
//
#include <hip/hip_runtime.h>
#include <hip/hip_bf16.h>
#include <math.h>

#define D_IN 256
#define D_H 128
#define D_L 64
#define NXCD 8

typedef __attribute__((ext_vector_type(8))) short bf16x8;
typedef __attribute__((ext_vector_type(4))) float f32x4;

__device__ __forceinline__ short f2bs(float f) {
    __hip_bfloat16 b = __float2bfloat16(f);
    return *reinterpret_cast<short*>(&b);
}
__device__ __forceinline__ float bs2f_lo(unsigned v) { return __uint_as_float(v << 16); }
__device__ __forceinline__ float bs2f_hi(unsigned v) { return __uint_as_float(v & 0xffff0000u); }

// ---------------- f32 -> bf16 elementwise (4/thread) ----------------
__global__ __launch_bounds__(256) void cvt_bf16_kernel(const float* __restrict__ in,
                                                       short* __restrict__ out, int n4) {
    int i = blockIdx.x * 256 + threadIdx.x;
    if (i < n4) {
        float4 v = ((const float4*)in)[i];
        short4 o;
        o.x = f2bs(v.x); o.y = f2bs(v.y); o.z = f2bs(v.z); o.w = f2bs(v.w);
        ((short4*)out)[i] = o;
    }
}

// ---------------- W[K][N] f32 -> WT[N][K] bf16 ----------------
__global__ __launch_bounds__(256) void cvt_wT_kernel(const float* __restrict__ W,
                                                     short* __restrict__ WT, int K, int N) {
    int t = blockIdx.x * 256 + threadIdx.x;
    if (t < K * N) {
        int k = t / N, n = t % N;
        WT[n * K + k] = f2bs(W[t]);
    }
}

// ---------------- Wf1 -> MFMA fragment layout bf16 ----------------
// fragW[(((kk*4+ct)*4+lg)*16+lr)*8 + j] = bf16(Wf1[(kk*32+lg*8+j)*64 + ct*16+lr])
__global__ __launch_bounds__(256) void cvt_wf1_kernel(const float* __restrict__ Wf1,
                                                      short* __restrict__ fragW) {
    int t = blockIdx.x * 256 + threadIdx.x;
    if (t < 8192) {
        int j  = t & 7;
        int lr = (t >> 3) & 15;
        int lg = (t >> 7) & 3;
        int ct = (t >> 9) & 3;
        int kk = (t >> 11) & 3;
        fragW[t] = f2bs(Wf1[(size_t)(kk * 32 + lg * 8 + j) * 64 + ct * 16 + lr]);
    }
}

// ---------------- degree: ungrouped, int4-vectorized, grid-stride ----------------
__global__ __launch_bounds__(256) void degree_v_kernel(const int* __restrict__ dst, int E,
                                                       int* __restrict__ degi) {
    const int nthr = gridDim.x * 256;
    const int tid = blockIdx.x * 256 + threadIdx.x;
    const int E4 = E >> 2;
    const int4* dst4 = (const int4*)dst;
    for (int i = tid; i < E4; i += nthr) {
        int4 d = dst4[i];
        atomicAdd(&degi[d.x], 1);
        atomicAdd(&degi[d.y], 1);
        atomicAdd(&degi[d.z], 1);
        atomicAdd(&degi[d.w], 1);
    }
    for (int e = E4 * 4 + tid; e < E; e += nthr) atomicAdd(&degi[dst[e]], 1);
}

__global__ __launch_bounds__(256) void rsqrt_kernel(const int* __restrict__ degi,
                                                    float* __restrict__ di, int n) {
    int i = blockIdx.x * 256 + threadIdx.x;
    if (i < n) di[i] = rsqrtf((float)degi[i] + 1.0f);
}

// ---------------- 3-phase hierarchical exclusive scan ----------------
__global__ __launch_bounds__(1024) void scan_blk_kernel(const int* __restrict__ degi,
                                                        int* __restrict__ rowptr,
                                                        int* __restrict__ bsum, int n) {
    __shared__ int sums[1024];
    const int tid = threadIdx.x;
    const int gid = blockIdx.x * 1024 + tid;
    int v = (gid < n) ? degi[gid] : 0;
    sums[tid] = v;
    __syncthreads();
    #pragma unroll
    for (int off = 1; off < 1024; off <<= 1) {
        int t = (tid >= off) ? sums[tid - off] : 0;
        __syncthreads();
        sums[tid] += t;
        __syncthreads();
    }
    if (gid < n) rowptr[gid] = sums[tid] - v;
    if (tid == 1023) bsum[blockIdx.x] = sums[1023];
}

__global__ __launch_bounds__(64) void scan_sums_kernel(int* __restrict__ bsum, int nb) {
    const int lane = threadIdx.x & 63;
    int carry = 0;
    for (int base = 0; base < nb; base += 64) {
        int idx = base + lane;
        int v = (idx < nb) ? bsum[idx] : 0;
        #pragma unroll
        for (int off = 1; off < 64; off <<= 1) {
            int t = __shfl_up(v, off, 64);
            if (lane >= off) v += t;
        }
        if (idx < nb) bsum[idx] = v + carry;
        carry += __shfl(v, 63, 64);
    }
}

__global__ __launch_bounds__(256) void scan_add_kernel(int* __restrict__ rowptr,
                                                       const int* __restrict__ bsum,
                                                       int* __restrict__ cursor, int n, int E) {
    const int gid = blockIdx.x * 256 + threadIdx.x;
    if (gid < n) {
        int b = gid >> 10;
        int off = (b > 0) ? bsum[b - 1] : 0;
        int r = rowptr[gid] + off;
        rowptr[gid] = r;
        cursor[gid] = r;
    }
    if (gid == 0) rowptr[n] = E;
}

// ---------------- CSR fill, XCD-range-grouped, int4-vectorized ----------------
__global__ __launch_bounds__(256) void fill_csr_x_kernel(const int* __restrict__ src,
                                                         const int* __restrict__ dst,
                                                         int* __restrict__ cursor,
                                                         int* __restrict__ csr_src,
                                                         int E, int npg) {
    const int grp = blockIdx.x & (NXCD - 1);
    const int nb = gridDim.x >> 3;
    const int bid = blockIdx.x >> 3;
    const int lo = grp * npg, hi = lo + npg;
    const int nthr = nb * 256;
    const int tid = bid * 256 + threadIdx.x;
    const int E4 = E >> 2;
    const int4* dst4 = (const int4*)dst;
    for (int i = tid; i < E4; i += nthr) {
        int4 d = dst4[i];
        int e = i * 4;
        if (d.x >= lo && d.x < hi) { int p = atomicAdd(&cursor[d.x], 1); csr_src[p] = src[e + 0]; }
        if (d.y >= lo && d.y < hi) { int p = atomicAdd(&cursor[d.y], 1); csr_src[p] = src[e + 1]; }
        if (d.z >= lo && d.z < hi) { int p = atomicAdd(&cursor[d.z], 1); csr_src[p] = src[e + 2]; }
        if (d.w >= lo && d.w < hi) { int p = atomicAdd(&cursor[d.w], 1); csr_src[p] = src[e + 3]; }
    }
    for (int e = E4 * 4 + tid; e < E; e += nthr) {
        int d = dst[e];
        if (d >= lo && d < hi) { int p = atomicAdd(&cursor[d], 1); csr_src[p] = src[e]; }
    }
}

// ---------------- MFMA GEMM: C[M,N]bf16 = A[M,K]bf16 @ BT[N,K]bf16 ----------------
template<int N, int K>
__global__ __launch_bounds__(256) void mfma_gemm_kernel(const short* __restrict__ A,
                                                        const short* __restrict__ BT,
                                                        short* __restrict__ C, int M) {
    const int tid = threadIdx.x;
    const int w = tid >> 6;
    const int l = tid & 63;
    const int lr = l & 15, lg = l >> 4;
    const int wr = w >> 1, wc = w & 1;
    const int bm = blockIdx.x * 64;
    constexpr int CT = (N / 2) / 16;
    f32x4 acc[2][CT] = {};
    const short* arow0 = A + (size_t)(bm + wr * 32 + lr) * K + lg * 8;
    const short* arow1 = arow0 + 16 * K;
    #pragma unroll
    for (int ks = 0; ks < K / 32; ++ks) {
        bf16x8 a0 = *(const bf16x8*)(arow0 + ks * 32);
        bf16x8 a1 = *(const bf16x8*)(arow1 + ks * 32);
        #pragma unroll
        for (int ct = 0; ct < CT; ++ct) {
            int col = wc * (N / 2) + ct * 16 + lr;
            bf16x8 b = *(const bf16x8*)(BT + (size_t)col * K + ks * 32 + lg * 8);
            acc[0][ct] = __builtin_amdgcn_mfma_f32_16x16x32_bf16(a0, b, acc[0][ct], 0, 0, 0);
            acc[1][ct] = __builtin_amdgcn_mfma_f32_16x16x32_bf16(a1, b, acc[1][ct], 0, 0, 0);
        }
    }
    #pragma unroll
    for (int i = 0; i < 2; ++i)
        #pragma unroll
        for (int ct = 0; ct < CT; ++ct)
            #pragma unroll
            for (int r = 0; r < 4; ++r) {
                int row = bm + wr * 32 + i * 16 + lg * 4 + r;
                int col = wc * (N / 2) + ct * 16 + lr;
                if (row < M) C[(size_t)row * N + col] = f2bs(acc[i][ct][r]);
            }
}

// ---------------- CSR aggregation (bf16 gather, f32 accumulate), 8x-unrolled ----------------
template<int D, bool RELU, bool OUT_BF16>
__global__ __launch_bounds__(256) void agg_kernel(const short* __restrict__ hb,
                                                  const int* __restrict__ rowptr,
                                                  const int* __restrict__ csr_src,
                                                  const float* __restrict__ di,
                                                  const float* __restrict__ bias,
                                                  float* __restrict__ outf,
                                                  short* __restrict__ outb, int N) {
    const int wave = (blockIdx.x * 256 + threadIdx.x) >> 6;
    const int lane = threadIdx.x & 63;
    if (wave >= N) return;
    const int d = wave;
    const int start = rowptr[d], end = rowptr[d + 1];
    const float did = di[d];
    if constexpr (D == 128) {
        const unsigned* h2 = (const unsigned*)hb;
        float ax = 0.f, ay = 0.f, bx = 0.f, by = 0.f;
        for (int base = start; base < end; base += 64) {
            int idx = base + lane;
            bool valid = idx < end;
            int mys = valid ? csr_src[idx] : 0;
            float myc = valid ? di[mys] * did : 0.f;
            int cnt = min(64, end - base);
            int j = 0;
            for (; j + 8 <= cnt; j += 8) {
                int s0 = __shfl(mys, j + 0, 64), s1 = __shfl(mys, j + 1, 64);
                int s2 = __shfl(mys, j + 2, 64), s3 = __shfl(mys, j + 3, 64);
                int s4 = __shfl(mys, j + 4, 64), s5 = __shfl(mys, j + 5, 64);
                int s6 = __shfl(mys, j + 6, 64), s7 = __shfl(mys, j + 7, 64);
                float c0 = __shfl(myc, j + 0, 64), c1 = __shfl(myc, j + 1, 64);
                float c2 = __shfl(myc, j + 2, 64), c3 = __shfl(myc, j + 3, 64);
                float c4 = __shfl(myc, j + 4, 64), c5 = __shfl(myc, j + 5, 64);
                float c6 = __shfl(myc, j + 6, 64), c7 = __shfl(myc, j + 7, 64);
                unsigned v0 = h2[(size_t)s0 * 64 + lane];
                unsigned v1 = h2[(size_t)s1 * 64 + lane];
                unsigned v2 = h2[(size_t)s2 * 64 + lane];
                unsigned v3 = h2[(size_t)s3 * 64 + lane];
                unsigned v4 = h2[(size_t)s4 * 64 + lane];
                unsigned v5 = h2[(size_t)s5 * 64 + lane];
                unsigned v6 = h2[(size_t)s6 * 64 + lane];
                unsigned v7 = h2[(size_t)s7 * 64 + lane];
                ax = fmaf(bs2f_lo(v0), c0, ax); ay = fmaf(bs2f_hi(v0), c0, ay);
                bx = fmaf(bs2f_lo(v1), c1, bx); by = fmaf(bs2f_hi(v1), c1, by);
                ax = fmaf(bs2f_lo(v2), c2, ax); ay = fmaf(bs2f_hi(v2), c2, ay);
                bx = fmaf(bs2f_lo(v3), c3, bx); by = fmaf(bs2f_hi(v3), c3, by);
                ax = fmaf(bs2f_lo(v4), c4, ax); ay = fmaf(bs2f_hi(v4), c4, ay);
                bx = fmaf(bs2f_lo(v5), c5, bx); by = fmaf(bs2f_hi(v5), c5, by);
                ax = fmaf(bs2f_lo(v6), c6, ax); ay = fmaf(bs2f_hi(v6), c6, ay);
                bx = fmaf(bs2f_lo(v7), c7, bx); by = fmaf(bs2f_hi(v7), c7, by);
            }
            for (; j < cnt; ++j) {
                int s = __shfl(mys, j, 64);
                float c = __shfl(myc, j, 64);
                unsigned v = h2[(size_t)s * 64 + lane];
                ax = fmaf(bs2f_lo(v), c, ax);
                ay = fmaf(bs2f_hi(v), c, ay);
            }
        }
        ax += bx; ay += by;
        float sl = did * did;
        unsigned hv = ((const unsigned*)hb)[(size_t)d * 64 + lane];
        float2 bv = ((const float2*)bias)[lane];
        float ox = ax + bs2f_lo(hv) * sl + bv.x;
        float oy = ay + bs2f_hi(hv) * sl + bv.y;
        if (RELU) { ox = fmaxf(ox, 0.f); oy = fmaxf(oy, 0.f); }
        if constexpr (OUT_BF16) {
            unsigned o = ((unsigned)(unsigned short)f2bs(oy) << 16) |
                         (unsigned)(unsigned short)f2bs(ox);
            ((unsigned*)outb)[(size_t)d * 64 + lane] = o;
        } else {
            ((float2*)outf)[(size_t)d * 64 + lane] = make_float2(ox, oy);
        }
    } else {
        const unsigned short* h1 = (const unsigned short*)hb;
        float a0 = 0.f, a1 = 0.f;
        for (int base = start; base < end; base += 64) {
            int idx = base + lane;
            bool valid = idx < end;
            int mys = valid ? csr_src[idx] : 0;
            float myc = valid ? di[mys] * did : 0.f;
            int cnt = min(64, end - base);
            int j = 0;
            for (; j + 8 <= cnt; j += 8) {
                int s0 = __shfl(mys, j + 0, 64), s1 = __shfl(mys, j + 1, 64);
                int s2 = __shfl(mys, j + 2, 64), s3 = __shfl(mys, j + 3, 64);
                int s4 = __shfl(mys, j + 4, 64), s5 = __shfl(mys, j + 5, 64);
                int s6 = __shfl(mys, j + 6, 64), s7 = __shfl(mys, j + 7, 64);
                float c0 = __shfl(myc, j + 0, 64), c1 = __shfl(myc, j + 1, 64);
                float c2 = __shfl(myc, j + 2, 64), c3 = __shfl(myc, j + 3, 64);
                float c4 = __shfl(myc, j + 4, 64), c5 = __shfl(myc, j + 5, 64);
                float c6 = __shfl(myc, j + 6, 64), c7 = __shfl(myc, j + 7, 64);
                unsigned short v0 = h1[(size_t)s0 * 64 + lane];
                unsigned short v1 = h1[(size_t)s1 * 64 + lane];
                unsigned short v2 = h1[(size_t)s2 * 64 + lane];
                unsigned short v3 = h1[(size_t)s3 * 64 + lane];
                unsigned short v4 = h1[(size_t)s4 * 64 + lane];
                unsigned short v5 = h1[(size_t)s5 * 64 + lane];
                unsigned short v6 = h1[(size_t)s6 * 64 + lane];
                unsigned short v7 = h1[(size_t)s7 * 64 + lane];
                a0 = fmaf(__uint_as_float((unsigned)v0 << 16), c0, a0);
                a1 = fmaf(__uint_as_float((unsigned)v1 << 16), c1, a1);
                a0 = fmaf(__uint_as_float((unsigned)v2 << 16), c2, a0);
                a1 = fmaf(__uint_as_float((unsigned)v3 << 16), c3, a1);
                a0 = fmaf(__uint_as_float((unsigned)v4 << 16), c4, a0);
                a1 = fmaf(__uint_as_float((unsigned)v5 << 16), c5, a1);
                a0 = fmaf(__uint_as_float((unsigned)v6 << 16), c6, a0);
                a1 = fmaf(__uint_as_float((unsigned)v7 << 16), c7, a1);
            }
            for (; j < cnt; ++j) {
                int s = __shfl(mys, j, 64);
                float c = __shfl(myc, j, 64);
                a0 = fmaf(__uint_as_float((unsigned)h1[(size_t)s * 64 + lane] << 16), c, a0);
            }
        }
        float acc = a0 + a1;
        float sl = did * did;
        float hd = __uint_as_float(((unsigned)h1[(size_t)d * 64 + lane]) << 16);
        float v = acc + hd * sl + bias[lane];
        if (RELU) v = fmaxf(v, 0.f);
        if constexpr (OUT_BF16) {
            outb[(size_t)d * 64 + lane] = f2bs(v);
        } else {
            outf[(size_t)d * 64 + lane] = v;
        }
    }
}

// ---------------- eval: gather z (bf16) + MFMA MLP + sigmoid ----------------
// r11: 256 edges/block (4 iter x 4 waves) for occupancy; fragment-layout Wf1 (bf16)
__global__ __launch_bounds__(256) void eval_mfma_kernel(const short* __restrict__ zb,
                                                        const int* __restrict__ es,
                                                        const int* __restrict__ ed,
                                                        const short* __restrict__ fragW,
                                                        const float* __restrict__ bf1,
                                                        const float* __restrict__ Wf2,
                                                        const float* __restrict__ bf2,
                                                        float* __restrict__ out, int EV) {
    const int tid = threadIdx.x;
    const int w = tid >> 6;
    const int l = tid & 63;
    const int lr = l & 15;
    const int lg = l >> 4;
    bf16x8 bfrag[4][4];
    #pragma unroll
    for (int kk = 0; kk < 4; ++kk)
        #pragma unroll
        for (int ct = 0; ct < 4; ++ct)
            bfrag[kk][ct] = *(const bf16x8*)&fragW[(size_t)((((kk * 4 + ct) * 4 + lg) * 16 + lr)) * 8];
    float b1r[4], w2r[4];
    #pragma unroll
    for (int ct = 0; ct < 4; ++ct) {
        b1r[ct] = bf1[ct * 16 + lr];
        w2r[ct] = Wf2[ct * 16 + lr];
    }
    const float b2v = bf2[0];

    const int eb = blockIdx.x * 256;
    #pragma unroll
    for (int t = 0; t < 4; ++t) {
        const int wbase = eb + t * 64 + w * 16;
        int edge = wbase + lr;
        int ec = edge < EV ? edge : 0;
        int ns = es[ec], nd = ed[ec];
        const short* za = zb + (size_t)ns * 64 + lg * 8;
        const short* zc = zb + (size_t)nd * 64 + lg * 8;
        bf16x8 a0 = *(const bf16x8*)(za);
        bf16x8 a1 = *(const bf16x8*)(za + 32);
        bf16x8 a2 = *(const bf16x8*)(zc);
        bf16x8 a3 = *(const bf16x8*)(zc + 32);
        float p0 = 0.f, p1 = 0.f, p2 = 0.f, p3 = 0.f;
        #pragma unroll
        for (int ct = 0; ct < 4; ++ct) {
            f32x4 acc = {0.f, 0.f, 0.f, 0.f};
            acc = __builtin_amdgcn_mfma_f32_16x16x32_bf16(a0, bfrag[0][ct], acc, 0, 0, 0);
            acc = __builtin_amdgcn_mfma_f32_16x16x32_bf16(a1, bfrag[1][ct], acc, 0, 0, 0);
            acc = __builtin_amdgcn_mfma_f32_16x16x32_bf16(a2, bfrag[2][ct], acc, 0, 0, 0);
            acc = __builtin_amdgcn_mfma_f32_16x16x32_bf16(a3, bfrag[3][ct], acc, 0, 0, 0);
            float h0 = fmaxf(acc[0] + b1r[ct], 0.f);
            float h1 = fmaxf(acc[1] + b1r[ct], 0.f);
            float h2 = fmaxf(acc[2] + b1r[ct], 0.f);
            float h3 = fmaxf(acc[3] + b1r[ct], 0.f);
            p0 = fmaf(h0, w2r[ct], p0);
            p1 = fmaf(h1, w2r[ct], p1);
            p2 = fmaf(h2, w2r[ct], p2);
            p3 = fmaf(h3, w2r[ct], p3);
        }
        #pragma unroll
        for (int m = 1; m < 16; m <<= 1) {
            p0 += __shfl_xor(p0, m, 64);
            p1 += __shfl_xor(p1, m, 64);
            p2 += __shfl_xor(p2, m, 64);
            p3 += __shfl_xor(p3, m, 64);
        }
        if (lr == 0) {
            int er = wbase + lg * 4;
            if (er + 0 < EV) out[er + 0] = 1.f / (1.f + expf(-(p0 + b2v)));
            if (er + 1 < EV) out[er + 1] = 1.f / (1.f + expf(-(p1 + b2v)));
            if (er + 2 < EV) out[er + 2] = 1.f / (1.f + expf(-(p2 + b2v)));
            if (er + 3 < EV) out[er + 3] = 1.f / (1.f + expf(-(p3 + b2v)));
        }
    }
}

extern "C" void kernel_launch(void* const* d_in, const int* in_sizes, int n_in,
                              void* d_out, int out_size, void* d_ws, size_t ws_size,
                              hipStream_t stream) {
    const float* x   = (const float*)d_in[0];
    const int* eidx  = (const int*)d_in[1];
    const int* evidx = (const int*)d_in[2];
    const float* W1  = (const float*)d_in[3];
    const float* b1  = (const float*)d_in[4];
    const float* W2  = (const float*)d_in[5];
    const float* b2  = (const float*)d_in[6];
    const float* Wf1 = (const float*)d_in[7];
    const float* bf1 = (const float*)d_in[8];
    const float* Wf2 = (const float*)d_in[9];
    const float* bf2 = (const float*)d_in[10];
    const int E  = in_sizes[1] / 2;
    const int EV = in_sizes[2] / 2;
    const int N  = in_sizes[0] / D_IN;
    const int* esrc = eidx;
    const int* edst = eidx + E;
    const int* es = evidx;
    const int* ed = evidx + EV;
    float* out = (float*)d_out;

    // workspace layout (bytes, max used ~46.8 MB):
    //   di 0 | degi 256K | rowptr 512K | cursor 768K | bsum 1000K
    //   csr_src 1M..7.4M | Wb1T @7500K (64K) | Wb2T @7700K (16K) | fragW @7800K (16K)
    //   xb   8M..33.6M (bf16 x)            [dead after gemm1]
    //   hb   8M..20.8M (bf16 h, over xb)   [agg1 out, gemm2 in]
    //   hlin2b 21M..27.4M                  [gemm2 out, agg2 in]
    //   hlinb 34M..46.8M                   [gemm1 out, agg1 in]
    //   zb   40M..46.4M (over hlinb)       [agg2 out, eval in]
    char* ws = (char*)d_ws;
    float* di     = (float*)(ws);
    int*   degi   = (int*)(ws + (256 << 10));
    int*   rowptr = (int*)(ws + (512 << 10));
    int*   cursor = (int*)(ws + (768 << 10));
    int*   bsum   = (int*)(ws + (1000 << 10));
    int*   csrsrc = (int*)(ws + (1 << 20));
    short* Wb1T   = (short*)(ws + (size_t)7500 * 1024);
    short* Wb2T   = (short*)(ws + (size_t)7700 * 1024);
    short* fragW  = (short*)(ws + (size_t)7800 * 1024);
    short* xb     = (short*)(ws + ((size_t)8 << 20));
    short* hb     = (short*)(ws + ((size_t)8 << 20));    // reuse after xb dead
    short* hlin2b = (short*)(ws + ((size_t)21 << 20));
    short* hlinb  = (short*)(ws + ((size_t)34 << 20));
    short* zb     = (short*)(ws + ((size_t)40 << 20));

    const int NB = (N + 1023) / 1024;
    const int NPG = (N + NXCD - 1) / NXCD;   // 6250

    // ---- weight/feature bf16 prep ----
    cvt_bf16_kernel<<<(N * D_IN / 4 + 255) / 256, 256, 0, stream>>>(x, xb, N * D_IN / 4);
    cvt_wT_kernel<<<(D_IN * D_H + 255) / 256, 256, 0, stream>>>(W1, Wb1T, D_IN, D_H);
    cvt_wT_kernel<<<(D_H * D_L + 255) / 256, 256, 0, stream>>>(W2, Wb2T, D_H, D_L);
    cvt_wf1_kernel<<<32, 256, 0, stream>>>(Wf1, fragW);

    // ---- CSR build ----
    hipMemsetAsync(degi, 0, (size_t)N * sizeof(int), stream);
    degree_v_kernel<<<2048, 256, 0, stream>>>(edst, E, degi);
    scan_blk_kernel<<<NB, 1024, 0, stream>>>(degi, rowptr, bsum, N);
    scan_sums_kernel<<<1, 64, 0, stream>>>(bsum, NB);
    scan_add_kernel<<<(N + 255) / 256, 256, 0, stream>>>(rowptr, bsum, cursor, N, E);
    rsqrt_kernel<<<(N + 255) / 256, 256, 0, stream>>>(degi, di, N);
    fill_csr_x_kernel<<<4096, 256, 0, stream>>>(esrc, edst, cursor, csrsrc, E, NPG);

    // ---- conv1: hlinb = bf16(xb@W1) ; agg+selfloop+b1+relu -> hb (bf16) ----
    mfma_gemm_kernel<D_H, D_IN><<<(N + 63) / 64, 256, 0, stream>>>(xb, Wb1T, hlinb, N);
    agg_kernel<128, true, true><<<(N + 3) / 4, 256, 0, stream>>>(
        hlinb, rowptr, csrsrc, di, b1, nullptr, hb, N);

    // ---- conv2: hlin2b = bf16(hb@W2) ; agg+selfloop+b2 -> zb (bf16) ----
    mfma_gemm_kernel<D_L, D_H><<<(N + 63) / 64, 256, 0, stream>>>(hb, Wb2T, hlin2b, N);
    agg_kernel<64, false, true><<<(N + 3) / 4, 256, 0, stream>>>(
        hlin2b, rowptr, csrsrc, di, b2, nullptr, zb, N);

    // ---- eval: MFMA MLP + sigmoid (256 edges/block) ----
    eval_mfma_kernel<<<(EV + 255) / 256, 256, 0, stream>>>(
        zb, es, ed, fragW, bf1, Wf2, bf2, out, EV);
}